// Round 1
// baseline (2455.919 us; speedup 1.0000x reference)
//
#include <hip/hip_runtime.h>
#include <math.h>

#define NB 16
#define NR 64
#define NCOL 64
#define ND 2048
#define DIM 512

// ---------------- workspace layout (float offsets) ----------------
#define OFF_RHNUM  0L
#define OFF_CHNUM  1024L
#define OFF_DCNUM  2048L
#define OFF_RHW    34816L
#define OFF_CHW    35840L
#define OFF_QROW   36864L
#define OFF_QCOL   45056L
#define OFF_PRER   53248L
#define OFF_PREC   577536L
#define OFF_INFORC 1101824L
#define OFF_BITS   2150400L
#define OFF_DCS    4247552L   // also aliased as aggdc (dcs dead by then)
#define OFF_PRESR  21024768L
#define WS_FLOATS  37801984L  // 151.2 MB

// ============ gate: sigmoid(node . w_node); for dc also write dcs = dm*g*dc ============
__global__ __launch_bounds__(256) void k_gate(
    const float* __restrict__ rh, const float* __restrict__ ch, const float* __restrict__ dc,
    const int* __restrict__ rm, const int* __restrict__ cm, const int* __restrict__ dmask,
    const float* __restrict__ wnode,
    float* __restrict__ rh_w, float* __restrict__ ch_w, float* __restrict__ dcs)
{
    int wave = threadIdx.x >> 6, lane = threadIdx.x & 63;
    long idx = (long)blockIdx.x * 4 + wave;   // < 34816
    const float* xrow; float* outw = nullptr; int mval; float* dcsrow = nullptr;
    if (idx < NB * NR) {
        int b = (int)(idx >> 6), r = (int)(idx & 63);
        xrow = rh + ((long)b * NR + r) * DIM; mval = rm[b * NR + r]; outw = rh_w + b * NR + r;
    } else if (idx < 2 * NB * NR) {
        long t = idx - NB * NR; int b = (int)(t >> 6), c = (int)(t & 63);
        xrow = ch + ((long)b * NCOL + c) * DIM; mval = cm[b * NCOL + c]; outw = ch_w + b * NCOL + c;
    } else {
        long t = idx - 2 * NB * NR; int b = (int)(t >> 11), j = (int)(t & 2047);
        xrow = dc + ((long)b * ND + j) * DIM; mval = dmask[b * ND + j];
        dcsrow = dcs + ((long)b * ND + j) * DIM;
    }
    const float4* px = (const float4*)xrow;
    const float4* pw = (const float4*)wnode;
    float4 xa = px[lane * 2], xb = px[lane * 2 + 1];
    float4 wa = pw[lane * 2], wb = pw[lane * 2 + 1];
    float s = xa.x * wa.x + xa.y * wa.y + xa.z * wa.z + xa.w * wa.w
            + xb.x * wb.x + xb.y * wb.y + xb.z * wb.z + xb.w * wb.w;
    #pragma unroll
    for (int o = 32; o > 0; o >>= 1) s += __shfl_xor(s, o, 64);
    float g = 1.f / (1.f + expf(-s));
    if (dcsrow) {
        float sc = mval ? g : 0.f;
        float4* pd = (float4*)dcsrow;
        float4 o0; o0.x = sc * xa.x; o0.y = sc * xa.y; o0.z = sc * xa.z; o0.w = sc * xa.w;
        float4 o1; o1.x = sc * xb.x; o1.y = sc * xb.y; o1.z = sc * xb.z; o1.w = sc * xb.w;
        pd[lane * 2] = o0; pd[lane * 2 + 1] = o1;
    } else if (lane == 0) {
        *outw = mval ? g : 0.f;
    }
}

// ============ q projections: qrow = q @ Wrq^T, qcol = q @ Wcq^T  (once) ============
__global__ __launch_bounds__(256) void k_q(
    const float* __restrict__ q, const float* __restrict__ wrq, const float* __restrict__ wcq,
    float* __restrict__ qrow, float* __restrict__ qcol)
{
    int b = blockIdx.z;
    const float* W = blockIdx.y ? wcq : wrq;
    float* out = blockIdx.y ? qcol : qrow;
    int wave = threadIdx.x >> 6, lane = threadIdx.x & 63;
    int n = blockIdx.x * 4 + wave;
    const float4* qp = (const float4*)(q + (long)b * DIM);
    const float4* wp = (const float4*)(W + (long)n * DIM);
    float4 a0 = qp[lane * 2], a1 = qp[lane * 2 + 1];
    float4 w0 = wp[lane * 2], w1 = wp[lane * 2 + 1];
    float s = a0.x * w0.x + a0.y * w0.y + a0.z * w0.z + a0.w * w0.w
            + a1.x * w1.x + a1.y * w1.y + a1.z * w1.z + a1.w * w1.w;
    #pragma unroll
    for (int o = 32; o > 0; o >>= 1) s += __shfl_xor(s, o, 64);
    if (lane == 0) out[(long)b * DIM + n] = s;
}

// ============ precompute: pack same_row graph bits + (srsum+scsum) partial dc_num ============
__global__ __launch_bounds__(256) void k_bits(
    const int* __restrict__ sr, const int* __restrict__ sc, const int* __restrict__ dmask,
    unsigned* __restrict__ bits, float* __restrict__ dcnum)
{
    long bi = blockIdx.x;                    // = b*ND + i
    int b = (int)(bi >> 11);
    const int* dmb = dmask + (long)b * ND;
    int dmi = dmb[bi & 2047];
    int wave = threadIdx.x >> 6, lane = threadIdx.x & 63;
    const int* srrow = sr + bi * ND;
    const int* scrow = sc + bi * ND;
    unsigned* brow = bits + bi * 64;
    int cnt = 0;
    for (int rr = 0; rr < 8; rr++) {
        int j = wave * 512 + rr * 64 + lane;
        int dmj = dmb[j] != 0;
        bool p1 = dmi && dmj && (srrow[j] != 0);
        unsigned long long m1 = __ballot(p1);
        bool p2 = dmi && dmj && (scrow[j] != 0);
        unsigned long long m2 = __ballot(p2);
        if (lane == 0) {
            int w0 = wave * 16 + rr * 2;
            brow[w0] = (unsigned)m1; brow[w0 + 1] = (unsigned)(m1 >> 32);
        }
        cnt += __popcll(m1) + __popcll(m2);
    }
    __shared__ int red[4];
    if (lane == 0) red[wave] = cnt;
    __syncthreads();
    if (threadIdx.x == 0) dcnum[bi] = (float)(red[0] + red[1] + red[2] + red[3]);
}

// ============ rh_num / ch_num ============
__global__ __launch_bounds__(256) void k_rcnum(
    const int* __restrict__ rel_rd, const int* __restrict__ rel_cd,
    const int* __restrict__ rm, const int* __restrict__ cm, const int* __restrict__ dmask,
    float* __restrict__ rh_num, float* __restrict__ ch_num)
{
    int wave = threadIdx.x >> 6, lane = threadIdx.x & 63;
    long idx = (long)blockIdx.x * 4 + wave;  // < 2048
    const int* row; int mval; float* out; const int* dmb;
    if (idx < NB * NR) {
        int b = (int)(idx >> 6), r = (int)(idx & 63);
        row = rel_rd + ((long)b * NR + r) * ND; mval = rm[b * NR + r];
        out = rh_num + b * NR + r; dmb = dmask + (long)b * ND;
    } else {
        long t = idx - NB * NR; int b = (int)(t >> 6), c = (int)(t & 63);
        row = rel_cd + ((long)b * NCOL + c) * ND; mval = cm[b * NCOL + c];
        out = ch_num + b * NCOL + c; dmb = dmask + (long)b * ND;
    }
    int cnt = 0;
    for (int rr = 0; rr < 32; rr++) {
        int j = rr * 64 + lane;
        cnt += (row[j] != 0 && dmb[j] != 0) ? 1 : 0;
    }
    #pragma unroll
    for (int o = 32; o > 0; o >>= 1) cnt += __shfl_xor(cnt, o, 64);
    if (lane == 0) {
        float s = mval ? (float)cnt : 0.f;
        *out = (s >= 1.f) ? (s + 1.f) : 1.f;
    }
}

// ============ finalize dc_num: add column sums of rh/ch graphs, transform ============
__global__ __launch_bounds__(256) void k_dcnum_final(
    const int* __restrict__ rel_rd, const int* __restrict__ rel_cd,
    const int* __restrict__ rm, const int* __restrict__ cm, const int* __restrict__ dmask,
    float* __restrict__ dcnum)
{
    int b = blockIdx.y;
    int j = blockIdx.x * 256 + threadIdx.x;
    const int* rd = rel_rd + (long)b * NR * ND;
    const int* cd = rel_cd + (long)b * NCOL * ND;
    const int* rmb = rm + b * NR;
    const int* cmb = cm + b * NCOL;
    int cnt = 0;
    for (int r = 0; r < NR; r++)  cnt += (rd[(long)r * ND + j] != 0 && rmb[r] != 0) ? 1 : 0;
    for (int c = 0; c < NCOL; c++) cnt += (cd[(long)c * ND + j] != 0 && cmb[c] != 0) ? 1 : 0;
    float add = (dmask[(long)b * ND + j] != 0) ? (float)cnt : 0.f;
    float t = dcnum[(long)b * ND + j] + add;
    dcnum[(long)b * ND + j] = (t >= 1.f) ? t : 1.f;
}

// ============ small dense GEMM: C[m,n] = epi( sum_k A[m,k]*W[n,k] ), M=64, N=K=512 ============
// EPI 1: C = alpha * rowscale[m] * acc
// EPI 2: C = relu( (acc + (mrow[m]!=0)*addvec[n]) / rownum[m] )
template<int EPI>
__global__ __launch_bounds__(256) void gemm_small(
    const float* __restrict__ A, long sA,
    const float* __restrict__ W,
    float* __restrict__ C, long sC,
    const float* __restrict__ rowscale, float alpha,
    const int* __restrict__ mrow, const float* __restrict__ addvec,
    const float* __restrict__ rownum, int rsb)
{
    int b = blockIdx.z;
    int n0 = blockIdx.x * 64;
    __shared__ float As[32][68], Ws[32][68];
    float acc[4][4] = {};
    int tx = threadIdx.x & 15, ty = threadIdx.x >> 4;
    int lm = threadIdx.x >> 2, lk = (threadIdx.x & 3) * 8;
    const float* Ab = A + (long)b * sA;
    for (int k0 = 0; k0 < DIM; k0 += 32) {
        const float4* pa = (const float4*)(Ab + (long)lm * DIM + k0 + lk);
        float4 va0 = pa[0], va1 = pa[1];
        const float4* pw = (const float4*)(W + (long)(n0 + lm) * DIM + k0 + lk);
        float4 vw0 = pw[0], vw1 = pw[1];
        As[lk + 0][lm] = va0.x; As[lk + 1][lm] = va0.y; As[lk + 2][lm] = va0.z; As[lk + 3][lm] = va0.w;
        As[lk + 4][lm] = va1.x; As[lk + 5][lm] = va1.y; As[lk + 6][lm] = va1.z; As[lk + 7][lm] = va1.w;
        Ws[lk + 0][lm] = vw0.x; Ws[lk + 1][lm] = vw0.y; Ws[lk + 2][lm] = vw0.z; Ws[lk + 3][lm] = vw0.w;
        Ws[lk + 4][lm] = vw1.x; Ws[lk + 5][lm] = vw1.y; Ws[lk + 6][lm] = vw1.z; Ws[lk + 7][lm] = vw1.w;
        __syncthreads();
        #pragma unroll
        for (int kk = 0; kk < 32; kk++) {
            float4 av = *(const float4*)&As[kk][ty * 4];
            float4 wv = *(const float4*)&Ws[kk][tx * 4];
            float a[4] = {av.x, av.y, av.z, av.w};
            float w[4] = {wv.x, wv.y, wv.z, wv.w};
            #pragma unroll
            for (int mi = 0; mi < 4; mi++)
                #pragma unroll
                for (int ni = 0; ni < 4; ni++)
                    acc[mi][ni] += a[mi] * w[ni];
        }
        __syncthreads();
    }
    #pragma unroll
    for (int mi = 0; mi < 4; mi++) {
        int gm = ty * 4 + mi;
        float vals[4];
        if (EPI == 1) {
            float sc = alpha * rowscale[(long)b * rsb + gm];
            #pragma unroll
            for (int ni = 0; ni < 4; ni++) vals[ni] = sc * acc[mi][ni];
        } else {
            float mq = (mrow[(long)b * rsb + gm] != 0) ? 1.f : 0.f;
            float inv = 1.f / rownum[(long)b * rsb + gm];
            #pragma unroll
            for (int ni = 0; ni < 4; ni++) {
                float t = (acc[mi][ni] + mq * addvec[(long)b * DIM + n0 + tx * 4 + ni]) * inv;
                vals[ni] = fmaxf(t, 0.f);
            }
        }
        float4 o; o.x = vals[0]; o.y = vals[1]; o.z = vals[2]; o.w = vals[3];
        *(float4*)(C + (long)b * sC + (long)gm * DIM + n0 + tx * 4) = o;
    }
}

// ============ pre_r / pre_c: [64 x 2048] int relation @ dcs[2048 x 512], row-masked ============
__global__ __launch_bounds__(256) void k_pre_rc(
    const int* __restrict__ rel_rd, const int* __restrict__ rel_cd,
    const float* __restrict__ dcs,
    const int* __restrict__ rm, const int* __restrict__ cm,
    float* __restrict__ pre_r, float* __restrict__ pre_c)
{
    int b = blockIdx.z, n0 = blockIdx.x * 64;
    const int* rel = blockIdx.y ? rel_cd : rel_rd;
    const int* msk = blockIdx.y ? cm : rm;
    float* outp = blockIdx.y ? pre_c : pre_r;
    __shared__ float As[64][68], Bs[64][68];
    float acc[4][4] = {};
    int tx = threadIdx.x & 15, ty = threadIdx.x >> 4;
    int am = threadIdx.x >> 2, ak = (threadIdx.x & 3) * 16;
    for (int k0 = 0; k0 < ND; k0 += 64) {
        const int4* pa = (const int4*)(rel + ((long)b * 64 + am) * ND + k0 + ak);
        #pragma unroll
        for (int s4 = 0; s4 < 4; s4++) {
            int4 v = pa[s4];
            As[ak + s4 * 4 + 0][am] = v.x ? 1.f : 0.f;
            As[ak + s4 * 4 + 1][am] = v.y ? 1.f : 0.f;
            As[ak + s4 * 4 + 2][am] = v.z ? 1.f : 0.f;
            As[ak + s4 * 4 + 3][am] = v.w ? 1.f : 0.f;
        }
        const float4* pb = (const float4*)(dcs + ((long)b * ND + k0 + am) * DIM + n0 + ak);
        #pragma unroll
        for (int s4 = 0; s4 < 4; s4++) *(float4*)&Bs[am][ak + s4 * 4] = pb[s4];
        __syncthreads();
        #pragma unroll 8
        for (int kk = 0; kk < 64; kk++) {
            float4 av = *(const float4*)&As[kk][ty * 4];
            float4 bv = *(const float4*)&Bs[kk][tx * 4];
            float a[4] = {av.x, av.y, av.z, av.w};
            float w[4] = {bv.x, bv.y, bv.z, bv.w};
            #pragma unroll
            for (int mi = 0; mi < 4; mi++)
                #pragma unroll
                for (int ni = 0; ni < 4; ni++)
                    acc[mi][ni] += a[mi] * w[ni];
        }
        __syncthreads();
    }
    #pragma unroll
    for (int mi = 0; mi < 4; mi++) {
        int gm = ty * 4 + mi;
        float sc = (msk[b * 64 + gm] != 0) ? 1.f : 0.f;
        float4 o; o.x = sc * acc[mi][0]; o.y = sc * acc[mi][1]; o.z = sc * acc[mi][2]; o.w = sc * acc[mi][3];
        *(float4*)(outp + ((long)b * 64 + gm) * DIM + n0 + tx * 4) = o;
    }
}

// ============ pre_sr = bits[2048 x 2048] @ dcs[2048 x 512]  (the big one) ============
__global__ __launch_bounds__(256) void k_pre_sr(
    const unsigned* __restrict__ bits, const float* __restrict__ dcs, float* __restrict__ out)
{
    int b = blockIdx.z, m0 = blockIdx.y * 128, n0 = blockIdx.x * 128;
    __shared__ float As[32][132], Bs[32][132];
    float acc[8][8] = {};
    int tx = threadIdx.x & 15, ty = threadIdx.x >> 4;
    int um = threadIdx.x >> 1, uh = threadIdx.x & 1;
    int bk = threadIdx.x >> 3, bn = (threadIdx.x & 7) * 16;
    for (int k0 = 0; k0 < ND; k0 += 32) {
        unsigned wrd = bits[((long)b * ND + m0 + um) * 64 + (k0 >> 5)];
        wrd >>= (uh * 16);
        #pragma unroll
        for (int s = 0; s < 16; s++) As[uh * 16 + s][um] = (float)((wrd >> s) & 1u);
        const float4* pb = (const float4*)(dcs + ((long)b * ND + k0 + bk) * DIM + n0 + bn);
        #pragma unroll
        for (int s = 0; s < 4; s++) *(float4*)&Bs[bk][bn + s * 4] = pb[s];
        __syncthreads();
        #pragma unroll 4
        for (int kk = 0; kk < 32; kk++) {
            float4 a0 = *(const float4*)&As[kk][ty * 8];
            float4 a1 = *(const float4*)&As[kk][ty * 8 + 4];
            float4 b0 = *(const float4*)&Bs[kk][tx * 8];
            float4 b1 = *(const float4*)&Bs[kk][tx * 8 + 4];
            float a[8] = {a0.x, a0.y, a0.z, a0.w, a1.x, a1.y, a1.z, a1.w};
            float w[8] = {b0.x, b0.y, b0.z, b0.w, b1.x, b1.y, b1.z, b1.w};
            #pragma unroll
            for (int mi = 0; mi < 8; mi++)
                #pragma unroll
                for (int ni = 0; ni < 8; ni++)
                    acc[mi][ni] += a[mi] * w[ni];
        }
        __syncthreads();
    }
    #pragma unroll
    for (int mi = 0; mi < 8; mi++) {
        int gm = m0 + ty * 8 + mi;
        float* po = out + ((long)b * ND + gm) * DIM + n0 + tx * 8;
        float4 o0; o0.x = acc[mi][0]; o0.y = acc[mi][1]; o0.z = acc[mi][2]; o0.w = acc[mi][3];
        float4 o1; o1.x = acc[mi][4]; o1.y = acc[mi][5]; o1.z = acc[mi][6]; o1.w = acc[mi][7];
        *(float4*)(po) = o0; *(float4*)(po + 4) = o1;
    }
}

// ============ aggdc = [rel_rd^T | rel_cd^T] (2048 x 128) @ info_rc (128 x 512), dm-masked ============
__global__ __launch_bounds__(256) void k_aggdc(
    const int* __restrict__ rel_rd, const int* __restrict__ rel_cd,
    const float* __restrict__ info_rc, const int* __restrict__ dmask,
    float* __restrict__ out)
{
    int b = blockIdx.z, m0 = blockIdx.y * 128, n0 = blockIdx.x * 128;
    __shared__ float As[32][132], Bs[32][132];
    float acc[8][8] = {};
    int tx = threadIdx.x & 15, ty = threadIdx.x >> 4;
    int ak = threadIdx.x >> 3, aj = (threadIdx.x & 7) * 16;
    for (int kt = 0; kt < 4; kt++) {
        const int* rel = (kt < 2) ? rel_rd : rel_cd;
        int krow = (kt & 1) * 32 + ak;
        const int4* pa = (const int4*)(rel + ((long)b * 64 + krow) * ND + m0 + aj);
        #pragma unroll
        for (int s = 0; s < 4; s++) {
            int4 v = pa[s];
            float4 f; f.x = v.x ? 1.f : 0.f; f.y = v.y ? 1.f : 0.f; f.z = v.z ? 1.f : 0.f; f.w = v.w ? 1.f : 0.f;
            *(float4*)&As[ak][aj + s * 4] = f;
        }
        const float4* pb = (const float4*)(info_rc + ((long)b * 128 + kt * 32 + ak) * DIM + n0 + aj);
        #pragma unroll
        for (int s = 0; s < 4; s++) *(float4*)&Bs[ak][aj + s * 4] = pb[s];
        __syncthreads();
        #pragma unroll 4
        for (int kk = 0; kk < 32; kk++) {
            float4 a0 = *(const float4*)&As[kk][ty * 8];
            float4 a1 = *(const float4*)&As[kk][ty * 8 + 4];
            float4 b0 = *(const float4*)&Bs[kk][tx * 8];
            float4 b1 = *(const float4*)&Bs[kk][tx * 8 + 4];
            float a[8] = {a0.x, a0.y, a0.z, a0.w, a1.x, a1.y, a1.z, a1.w};
            float w[8] = {b0.x, b0.y, b0.z, b0.w, b1.x, b1.y, b1.z, b1.w};
            #pragma unroll
            for (int mi = 0; mi < 8; mi++)
                #pragma unroll
                for (int ni = 0; ni < 8; ni++)
                    acc[mi][ni] += a[mi] * w[ni];
        }
        __syncthreads();
    }
    #pragma unroll
    for (int mi = 0; mi < 8; mi++) {
        int gm = m0 + ty * 8 + mi;
        float mq = (dmask[(long)b * ND + gm] != 0) ? 1.f : 0.f;
        float* po = out + ((long)b * ND + gm) * DIM + n0 + tx * 8;
        float4 o0; o0.x = mq * acc[mi][0]; o0.y = mq * acc[mi][1]; o0.z = mq * acc[mi][2]; o0.w = mq * acc[mi][3];
        float4 o1; o1.x = mq * acc[mi][4]; o1.y = mq * acc[mi][5]; o1.z = mq * acc[mi][6]; o1.w = mq * acc[mi][7];
        *(float4*)(po) = o0; *(float4*)(po + 4) = o1;
    }
}

// ============ dc projection + combine: out = relu((pre_sr @ W_sr^T + aggdc) / dc_num) ============
__global__ __launch_bounds__(256) void k_proj_dc(
    const float* __restrict__ A, const float* __restrict__ W,
    const float* __restrict__ addm, const float* __restrict__ rownum,
    float* __restrict__ out)
{
    int b = blockIdx.z, m0 = blockIdx.y * 128, n0 = blockIdx.x * 128;
    __shared__ float As[32][132], Ws2[32][132];
    float acc[8][8] = {};
    int tx = threadIdx.x & 15, ty = threadIdx.x >> 4;
    int am = threadIdx.x >> 1, ah = (threadIdx.x & 1) * 16;
    for (int k0 = 0; k0 < DIM; k0 += 32) {
        const float4* pa = (const float4*)(A + ((long)b * ND + m0 + am) * DIM + k0 + ah);
        float4 v0 = pa[0], v1 = pa[1], v2 = pa[2], v3 = pa[3];
        As[ah + 0][am] = v0.x;  As[ah + 1][am] = v0.y;  As[ah + 2][am] = v0.z;  As[ah + 3][am] = v0.w;
        As[ah + 4][am] = v1.x;  As[ah + 5][am] = v1.y;  As[ah + 6][am] = v1.z;  As[ah + 7][am] = v1.w;
        As[ah + 8][am] = v2.x;  As[ah + 9][am] = v2.y;  As[ah + 10][am] = v2.z; As[ah + 11][am] = v2.w;
        As[ah + 12][am] = v3.x; As[ah + 13][am] = v3.y; As[ah + 14][am] = v3.z; As[ah + 15][am] = v3.w;
        const float4* pw = (const float4*)(W + (long)(n0 + am) * DIM + k0 + ah);
        v0 = pw[0]; v1 = pw[1]; v2 = pw[2]; v3 = pw[3];
        Ws2[ah + 0][am] = v0.x;  Ws2[ah + 1][am] = v0.y;  Ws2[ah + 2][am] = v0.z;  Ws2[ah + 3][am] = v0.w;
        Ws2[ah + 4][am] = v1.x;  Ws2[ah + 5][am] = v1.y;  Ws2[ah + 6][am] = v1.z;  Ws2[ah + 7][am] = v1.w;
        Ws2[ah + 8][am] = v2.x;  Ws2[ah + 9][am] = v2.y;  Ws2[ah + 10][am] = v2.z; Ws2[ah + 11][am] = v2.w;
        Ws2[ah + 12][am] = v3.x; Ws2[ah + 13][am] = v3.y; Ws2[ah + 14][am] = v3.z; Ws2[ah + 15][am] = v3.w;
        __syncthreads();
        #pragma unroll 4
        for (int kk = 0; kk < 32; kk++) {
            float4 a0 = *(const float4*)&As[kk][ty * 8];
            float4 a1 = *(const float4*)&As[kk][ty * 8 + 4];
            float4 b0 = *(const float4*)&Ws2[kk][tx * 8];
            float4 b1 = *(const float4*)&Ws2[kk][tx * 8 + 4];
            float a[8] = {a0.x, a0.y, a0.z, a0.w, a1.x, a1.y, a1.z, a1.w};
            float w[8] = {b0.x, b0.y, b0.z, b0.w, b1.x, b1.y, b1.z, b1.w};
            #pragma unroll
            for (int mi = 0; mi < 8; mi++)
                #pragma unroll
                for (int ni = 0; ni < 8; ni++)
                    acc[mi][ni] += a[mi] * w[ni];
        }
        __syncthreads();
    }
    #pragma unroll
    for (int mi = 0; mi < 8; mi++) {
        int gm = m0 + ty * 8 + mi;
        float inv = 1.f / rownum[(long)b * ND + gm];
        const float4* pad = (const float4*)(addm + ((long)b * ND + gm) * DIM + n0 + tx * 8);
        float4 d0 = pad[0], d1 = pad[1];
        float* po = out + ((long)b * ND + gm) * DIM + n0 + tx * 8;
        float4 o0, o1;
        o0.x = fmaxf((acc[mi][0] + d0.x) * inv, 0.f);
        o0.y = fmaxf((acc[mi][1] + d0.y) * inv, 0.f);
        o0.z = fmaxf((acc[mi][2] + d0.z) * inv, 0.f);
        o0.w = fmaxf((acc[mi][3] + d0.w) * inv, 0.f);
        o1.x = fmaxf((acc[mi][4] + d1.x) * inv, 0.f);
        o1.y = fmaxf((acc[mi][5] + d1.y) * inv, 0.f);
        o1.z = fmaxf((acc[mi][6] + d1.z) * inv, 0.f);
        o1.w = fmaxf((acc[mi][7] + d1.w) * inv, 0.f);
        *(float4*)(po) = o0; *(float4*)(po + 4) = o1;
    }
}

// ==================================================================================
extern "C" void kernel_launch(void* const* d_in, const int* in_sizes, int n_in,
                              void* d_out, int out_size, void* d_ws, size_t ws_size,
                              hipStream_t stream)
{
    const float* q       = (const float*)d_in[0];
    const float* rh0     = (const float*)d_in[1];
    const float* ch0     = (const float*)d_in[2];
    const float* dc0     = (const float*)d_in[3];
    const int*   rm      = (const int*)d_in[4];
    const int*   cm      = (const int*)d_in[5];
    const int*   dmask   = (const int*)d_in[6];
    const int*   same_row= (const int*)d_in[7];
    const int*   same_col= (const int*)d_in[8];
    const int*   rel_rd  = (const int*)d_in[9];
    const int*   rel_cd  = (const int*)d_in[10];
    const float* wnode   = (const float*)d_in[11];
    const float* w_rdc   = (const float*)d_in[12];
    const float* w_cdc   = (const float*)d_in[13];
    const float* w_dcr   = (const float*)d_in[14];
    const float* w_dcc   = (const float*)d_in[15];
    const float* w_sr    = (const float*)d_in[16];
    const float* w_rq    = (const float*)d_in[18];
    const float* w_cq    = (const float*)d_in[19];

    float* out = (float*)d_out;
    float* rh = out;                           // [16,64,512]
    float* ch = out + (long)NB * NR * DIM;     // [16,64,512]
    float* dc = out + (long)NB * NR * DIM * 2; // [16,2048,512]

    if (ws_size < (size_t)WS_FLOATS * 4) return;  // need 151.2 MB scratch

    float* ws      = (float*)d_ws;
    float* rh_num  = ws + OFF_RHNUM;
    float* ch_num  = ws + OFF_CHNUM;
    float* dc_num  = ws + OFF_DCNUM;
    float* rh_w    = ws + OFF_RHW;
    float* ch_w    = ws + OFF_CHW;
    float* qrow    = ws + OFF_QROW;
    float* qcol    = ws + OFF_QCOL;
    float* pre_r   = ws + OFF_PRER;
    float* pre_c   = ws + OFF_PREC;
    float* info_rc = ws + OFF_INFORC;
    unsigned* bits = (unsigned*)(ws + OFF_BITS);
    float* dcs     = ws + OFF_DCS;
    float* aggdc   = dcs;                      // alias: dcs dead before k_aggdc writes
    float* pre_sr  = ws + OFF_PRESR;

    // initial node states into the output slices (they carry state between iterations)
    hipMemcpyAsync(rh, rh0, sizeof(float) * (size_t)NB * NR * DIM, hipMemcpyDeviceToDevice, stream);
    hipMemcpyAsync(ch, ch0, sizeof(float) * (size_t)NB * NCOL * DIM, hipMemcpyDeviceToDevice, stream);
    hipMemcpyAsync(dc, dc0, sizeof(float) * (size_t)NB * ND * DIM, hipMemcpyDeviceToDevice, stream);

    // ---- precompute (degrees, graph bits, q projections) ----
    k_bits<<<NB * ND, 256, 0, stream>>>(same_row, same_col, dmask, bits, dc_num);
    k_rcnum<<<512, 256, 0, stream>>>(rel_rd, rel_cd, rm, cm, dmask, rh_num, ch_num);
    k_dcnum_final<<<dim3(ND / 256, NB), 256, 0, stream>>>(rel_rd, rel_cd, rm, cm, dmask, dc_num);
    k_q<<<dim3(128, 2, NB), 256, 0, stream>>>(q, w_rq, w_cq, qrow, qcol);

    for (int it = 0; it < 2; it++) {
        k_gate<<<8704, 256, 0, stream>>>(rh, ch, dc, rm, cm, dmask, wnode, rh_w, ch_w, dcs);
        // info_r = rh_w[r] * (rh @ w_dcr^T); info_c = 2 * ch_w[c] * (ch @ w_dcc^T)
        gemm_small<1><<<dim3(8, 1, NB), 256, 0, stream>>>(rh, (long)NR * DIM, w_dcr,
            info_rc, 128L * DIM, rh_w, 1.0f, nullptr, nullptr, nullptr, NR);
        gemm_small<1><<<dim3(8, 1, NB), 256, 0, stream>>>(ch, (long)NCOL * DIM, w_dcc,
            info_rc + 64L * DIM, 128L * DIM, ch_w, 2.0f, nullptr, nullptr, nullptr, NCOL);
        // big masked aggregation over data cells
        k_pre_sr<<<dim3(4, 16, NB), 256, 0, stream>>>(bits, dcs, pre_sr);
        k_pre_rc<<<dim3(8, 2, NB), 256, 0, stream>>>(rel_rd, rel_cd, dcs, rm, cm, pre_r, pre_c);
        // dc-side aggregation of header infos (writes aggdc, aliasing dcs - now dead)
        k_aggdc<<<dim3(4, 16, NB), 256, 0, stream>>>(rel_rd, rel_cd, info_rc, dmask, aggdc);
        // header updates: relu((pre @ W^T + mask*qvec)/num)
        gemm_small<2><<<dim3(8, 1, NB), 256, 0, stream>>>(pre_r, (long)NR * DIM, w_rdc,
            rh, (long)NR * DIM, nullptr, 1.0f, rm, qrow, rh_num, NR);
        gemm_small<2><<<dim3(8, 1, NB), 256, 0, stream>>>(pre_c, (long)NCOL * DIM, w_cdc,
            ch, (long)NCOL * DIM, nullptr, 1.0f, cm, qcol, ch_num, NCOL);
        // dc update: relu((pre_sr @ w_sr^T + aggdc)/dc_num)
        k_proj_dc<<<dim3(4, 16, NB), 256, 0, stream>>>(pre_sr, w_sr, aggdc, dc_num, dc);
    }
}

// Round 2
// 1473.288 us; speedup vs baseline: 1.6670x; 1.6670x over previous
//
#include <hip/hip_runtime.h>
#include <math.h>

#define NB 16
#define NR 64
#define NCOL 64
#define ND 2048
#define DIM 512

typedef __attribute__((ext_vector_type(4))) float f32x4;
typedef __attribute__((ext_vector_type(8))) short bf16x8;
typedef __attribute__((ext_vector_type(8))) unsigned short us8;

// ---------------- workspace layout (float offsets) ----------------
#define OFF_RHNUM  0L
#define OFF_CHNUM  1024L
#define OFF_DCNUM  2048L
#define OFF_RHW    34816L
#define OFF_CHW    35840L
#define OFF_QROW   36864L
#define OFF_QCOL   45056L
#define OFF_PRER   53248L
#define OFF_PREC   577536L
#define OFF_INFORC 1101824L
#define OFF_BITS   2150400L
#define OFF_DCS    4247552L   // bf16 planes thi+tlo; later aliased as aggdc
#define OFF_PRESR  21024768L
#define WS_FLOATS  37801984L  // 151.2 MB (unchanged from R1)

// ============ gate for rh/ch rows: sigmoid(node . w_node), masked ============
__global__ __launch_bounds__(256) void k_gate_rc(
    const float* __restrict__ rh, const float* __restrict__ ch,
    const int* __restrict__ rm, const int* __restrict__ cm,
    const float* __restrict__ wnode,
    float* __restrict__ rh_w, float* __restrict__ ch_w)
{
    int wave = threadIdx.x >> 6, lane = threadIdx.x & 63;
    int idx = blockIdx.x * 4 + wave;   // < 2048
    const float* xrow; float* outw; int mval;
    if (idx < NB * NR) {
        int b = idx >> 6, r = idx & 63;
        xrow = rh + ((long)b * NR + r) * DIM; mval = rm[b * NR + r]; outw = rh_w + b * NR + r;
    } else {
        int tt = idx - NB * NR; int b = tt >> 6, c = tt & 63;
        xrow = ch + ((long)b * NCOL + c) * DIM; mval = cm[b * NCOL + c]; outw = ch_w + b * NCOL + c;
    }
    const float4* px = (const float4*)xrow;
    const float4* pw = (const float4*)wnode;
    float4 xa = px[lane * 2], xb = px[lane * 2 + 1];
    float4 wa = pw[lane * 2], wb = pw[lane * 2 + 1];
    float s = xa.x * wa.x + xa.y * wa.y + xa.z * wa.z + xa.w * wa.w
            + xb.x * wb.x + xb.y * wb.y + xb.z * wb.z + xb.w * wb.w;
    #pragma unroll
    for (int o = 32; o > 0; o >>= 1) s += __shfl_xor(s, o, 64);
    if (lane == 0) {
        float g = 1.f / (1.f + expf(-s));
        *outw = mval ? g : 0.f;
    }
}

// ============ split+transpose: dc -> gated bf16 hi/lo planes [b][512][2048] ============
__global__ __launch_bounds__(256) void k_split_t(
    const float* __restrict__ dc, const float* __restrict__ wnode, const int* __restrict__ dmask,
    unsigned short* __restrict__ thi, unsigned short* __restrict__ tlo)
{
    int b = blockIdx.y, j0 = blockIdx.x * 16;
    __shared__ float X[16 * 512];
    __shared__ float sc[16];
    int t = threadIdx.x;
    int r = t >> 4, u = t & 15;
    const float* row = dc + ((long)b * ND + j0 + r) * DIM;
    float part = 0.f;
    #pragma unroll
    for (int i = 0; i < 8; i++) {
        int col = i * 64 + u * 4;
        float4 v = *(const float4*)(row + col);
        float4 w = *(const float4*)(wnode + col);
        part += v.x * w.x + v.y * w.y + v.z * w.z + v.w * w.w;
        // XOR-swizzle by (r&7)*4: multiple of 4, keeps float4 contiguity, spreads banks
        *(float4*)&X[r * 512 + (col ^ ((r & 7) * 4))] = v;
    }
    part += __shfl_xor(part, 1, 64);
    part += __shfl_xor(part, 2, 64);
    part += __shfl_xor(part, 4, 64);
    part += __shfl_xor(part, 8, 64);
    if (u == 0) {
        float g = 1.f / (1.f + expf(-part));
        sc[r] = (dmask[(long)b * ND + j0 + r] != 0) ? g : 0.f;
    }
    __syncthreads();
    #pragma unroll
    for (int h = 0; h < 2; h++) {
        int n = t + h * 256;
        us8 ph0, ph1, pl0, pl1;
        #pragma unroll
        for (int rr = 0; rr < 16; rr++) {
            float v = X[rr * 512 + (n ^ ((rr & 7) * 4))] * sc[rr];
            unsigned uv = __float_as_uint(v);
            unsigned hb = (uv + 0x7FFFu + ((uv >> 16) & 1u)) >> 16;   // RNE to bf16
            float lo = v - __uint_as_float(hb << 16);
            unsigned lv = __float_as_uint(lo);
            unsigned lb = (lv + 0x7FFFu + ((lv >> 16) & 1u)) >> 16;
            if (rr < 8) { ph0[rr] = (unsigned short)hb; pl0[rr] = (unsigned short)lb; }
            else        { ph1[rr - 8] = (unsigned short)hb; pl1[rr - 8] = (unsigned short)lb; }
        }
        long ob = ((long)b * DIM + n) * ND + j0;
        *(us8*)(thi + ob) = ph0; *(us8*)(thi + ob + 8) = ph1;
        *(us8*)(tlo + ob) = pl0; *(us8*)(tlo + ob + 8) = pl1;
    }
}

// ============ q projections (once) ============
__global__ __launch_bounds__(256) void k_q(
    const float* __restrict__ q, const float* __restrict__ wrq, const float* __restrict__ wcq,
    float* __restrict__ qrow, float* __restrict__ qcol)
{
    int b = blockIdx.z;
    const float* W = blockIdx.y ? wcq : wrq;
    float* out = blockIdx.y ? qcol : qrow;
    int wave = threadIdx.x >> 6, lane = threadIdx.x & 63;
    int n = blockIdx.x * 4 + wave;
    const float4* qp = (const float4*)(q + (long)b * DIM);
    const float4* wp = (const float4*)(W + (long)n * DIM);
    float4 a0 = qp[lane * 2], a1 = qp[lane * 2 + 1];
    float4 w0 = wp[lane * 2], w1 = wp[lane * 2 + 1];
    float s = a0.x * w0.x + a0.y * w0.y + a0.z * w0.z + a0.w * w0.w
            + a1.x * w1.x + a1.y * w1.y + a1.z * w1.z + a1.w * w1.w;
    #pragma unroll
    for (int o = 32; o > 0; o >>= 1) s += __shfl_xor(s, o, 64);
    if (lane == 0) out[(long)b * DIM + n] = s;
}

// ============ precompute: pack same_row graph bits + (srsum+scsum) partial dc_num ============
__global__ __launch_bounds__(256) void k_bits(
    const int* __restrict__ sr, const int* __restrict__ sc, const int* __restrict__ dmask,
    unsigned* __restrict__ bits, float* __restrict__ dcnum)
{
    long bi = blockIdx.x;                    // = b*ND + i
    int b = (int)(bi >> 11);
    const int* dmb = dmask + (long)b * ND;
    int dmi = dmb[bi & 2047];
    int wave = threadIdx.x >> 6, lane = threadIdx.x & 63;
    const int* srrow = sr + bi * ND;
    const int* scrow = sc + bi * ND;
    unsigned* brow = bits + bi * 64;
    int cnt = 0;
    for (int rr = 0; rr < 8; rr++) {
        int j = wave * 512 + rr * 64 + lane;
        int dmj = dmb[j] != 0;
        bool p1 = dmi && dmj && (srrow[j] != 0);
        unsigned long long m1 = __ballot(p1);
        bool p2 = dmi && dmj && (scrow[j] != 0);
        unsigned long long m2 = __ballot(p2);
        if (lane == 0) {
            int w0 = wave * 16 + rr * 2;
            brow[w0] = (unsigned)m1; brow[w0 + 1] = (unsigned)(m1 >> 32);
        }
        cnt += __popcll(m1) + __popcll(m2);
    }
    __shared__ int red[4];
    if (lane == 0) red[wave] = cnt;
    __syncthreads();
    if (threadIdx.x == 0) dcnum[bi] = (float)(red[0] + red[1] + red[2] + red[3]);
}

// ============ rh_num / ch_num ============
__global__ __launch_bounds__(256) void k_rcnum(
    const int* __restrict__ rel_rd, const int* __restrict__ rel_cd,
    const int* __restrict__ rm, const int* __restrict__ cm, const int* __restrict__ dmask,
    float* __restrict__ rh_num, float* __restrict__ ch_num)
{
    int wave = threadIdx.x >> 6, lane = threadIdx.x & 63;
    long idx = (long)blockIdx.x * 4 + wave;  // < 2048
    const int* row; int mval; float* out; const int* dmb;
    if (idx < NB * NR) {
        int b = (int)(idx >> 6), r = (int)(idx & 63);
        row = rel_rd + ((long)b * NR + r) * ND; mval = rm[b * NR + r];
        out = rh_num + b * NR + r; dmb = dmask + (long)b * ND;
    } else {
        long tt = idx - NB * NR; int b = (int)(tt >> 6), c = (int)(tt & 63);
        row = rel_cd + ((long)b * NCOL + c) * ND; mval = cm[b * NCOL + c];
        out = ch_num + b * NCOL + c; dmb = dmask + (long)b * ND;
    }
    int cnt = 0;
    for (int rr = 0; rr < 32; rr++) {
        int j = rr * 64 + lane;
        cnt += (row[j] != 0 && dmb[j] != 0) ? 1 : 0;
    }
    #pragma unroll
    for (int o = 32; o > 0; o >>= 1) cnt += __shfl_xor(cnt, o, 64);
    if (lane == 0) {
        float s = mval ? (float)cnt : 0.f;
        *out = (s >= 1.f) ? (s + 1.f) : 1.f;
    }
}

// ============ finalize dc_num ============
__global__ __launch_bounds__(256) void k_dcnum_final(
    const int* __restrict__ rel_rd, const int* __restrict__ rel_cd,
    const int* __restrict__ rm, const int* __restrict__ cm, const int* __restrict__ dmask,
    float* __restrict__ dcnum)
{
    int b = blockIdx.y;
    int j = blockIdx.x * 256 + threadIdx.x;
    const int* rd = rel_rd + (long)b * NR * ND;
    const int* cd = rel_cd + (long)b * NCOL * ND;
    const int* rmb = rm + b * NR;
    const int* cmb = cm + b * NCOL;
    int cnt = 0;
    for (int r = 0; r < NR; r++)  cnt += (rd[(long)r * ND + j] != 0 && rmb[r] != 0) ? 1 : 0;
    for (int c = 0; c < NCOL; c++) cnt += (cd[(long)c * ND + j] != 0 && cmb[c] != 0) ? 1 : 0;
    float add = (dmask[(long)b * ND + j] != 0) ? (float)cnt : 0.f;
    float tv = dcnum[(long)b * ND + j] + add;
    dcnum[(long)b * ND + j] = (tv >= 1.f) ? tv : 1.f;
}

// ============ small dense GEMM: M=64, N=K=512 (EPI1: scale; EPI2: +q, /num, relu) ============
template<int EPI>
__global__ __launch_bounds__(256) void gemm_small(
    const float* __restrict__ A, long sA,
    const float* __restrict__ W,
    float* __restrict__ C, long sC,
    const float* __restrict__ rowscale, float alpha,
    const int* __restrict__ mrow, const float* __restrict__ addvec,
    const float* __restrict__ rownum, int rsb)
{
    int b = blockIdx.z;
    int n0 = blockIdx.x * 64;
    __shared__ float As[32][68], Ws[32][68];
    float acc[4][4] = {};
    int tx = threadIdx.x & 15, ty = threadIdx.x >> 4;
    int lm = threadIdx.x >> 2, lk = (threadIdx.x & 3) * 8;
    const float* Ab = A + (long)b * sA;
    for (int k0 = 0; k0 < DIM; k0 += 32) {
        const float4* pa = (const float4*)(Ab + (long)lm * DIM + k0 + lk);
        float4 va0 = pa[0], va1 = pa[1];
        const float4* pw = (const float4*)(W + (long)(n0 + lm) * DIM + k0 + lk);
        float4 vw0 = pw[0], vw1 = pw[1];
        As[lk + 0][lm] = va0.x; As[lk + 1][lm] = va0.y; As[lk + 2][lm] = va0.z; As[lk + 3][lm] = va0.w;
        As[lk + 4][lm] = va1.x; As[lk + 5][lm] = va1.y; As[lk + 6][lm] = va1.z; As[lk + 7][lm] = va1.w;
        Ws[lk + 0][lm] = vw0.x; Ws[lk + 1][lm] = vw0.y; Ws[lk + 2][lm] = vw0.z; Ws[lk + 3][lm] = vw0.w;
        Ws[lk + 4][lm] = vw1.x; Ws[lk + 5][lm] = vw1.y; Ws[lk + 6][lm] = vw1.z; Ws[lk + 7][lm] = vw1.w;
        __syncthreads();
        #pragma unroll
        for (int kk = 0; kk < 32; kk++) {
            float4 av = *(const float4*)&As[kk][ty * 4];
            float4 wv = *(const float4*)&Ws[kk][tx * 4];
            float a[4] = {av.x, av.y, av.z, av.w};
            float w[4] = {wv.x, wv.y, wv.z, wv.w};
            #pragma unroll
            for (int mi = 0; mi < 4; mi++)
                #pragma unroll
                for (int ni = 0; ni < 4; ni++)
                    acc[mi][ni] += a[mi] * w[ni];
        }
        __syncthreads();
    }
    #pragma unroll
    for (int mi = 0; mi < 4; mi++) {
        int gm = ty * 4 + mi;
        float vals[4];
        if (EPI == 1) {
            float scv = alpha * rowscale[(long)b * rsb + gm];
            #pragma unroll
            for (int ni = 0; ni < 4; ni++) vals[ni] = scv * acc[mi][ni];
        } else {
            float mq = (mrow[(long)b * rsb + gm] != 0) ? 1.f : 0.f;
            float inv = 1.f / rownum[(long)b * rsb + gm];
            #pragma unroll
            for (int ni = 0; ni < 4; ni++) {
                float tv = (acc[mi][ni] + mq * addvec[(long)b * DIM + n0 + tx * 4 + ni]) * inv;
                vals[ni] = fmaxf(tv, 0.f);
            }
        }
        float4 o; o.x = vals[0]; o.y = vals[1]; o.z = vals[2]; o.w = vals[3];
        *(float4*)(C + (long)b * sC + (long)gm * DIM + n0 + tx * 4) = o;
    }
}

// ============ pre_r / pre_c from bf16 planes: [64 x 2048] rel @ (hi+lo)[2048 x 512] ============
__global__ __launch_bounds__(256) void k_pre_rc(
    const int* __restrict__ rel_rd, const int* __restrict__ rel_cd,
    const unsigned short* __restrict__ thi, const unsigned short* __restrict__ tlo,
    const int* __restrict__ rm, const int* __restrict__ cm,
    float* __restrict__ pre_r, float* __restrict__ pre_c)
{
    int b = blockIdx.z, n0 = blockIdx.x * 64;
    const int* rel = blockIdx.y ? rel_cd : rel_rd;
    const int* msk = blockIdx.y ? cm : rm;
    float* outp = blockIdx.y ? pre_c : pre_r;
    __shared__ float As[64][68], Bs[64][68];
    float acc[4][4] = {};
    int tx = threadIdx.x & 15, ty = threadIdx.x >> 4;
    int am = threadIdx.x >> 2, ak = (threadIdx.x & 3) * 16;
    int bn = threadIdx.x & 63, bseg = threadIdx.x >> 6;
    for (int k0 = 0; k0 < ND; k0 += 64) {
        const int4* pa = (const int4*)(rel + ((long)b * 64 + am) * ND + k0 + ak);
        #pragma unroll
        for (int s4 = 0; s4 < 4; s4++) {
            int4 v = pa[s4];
            As[ak + s4 * 4 + 0][am] = v.x ? 1.f : 0.f;
            As[ak + s4 * 4 + 1][am] = v.y ? 1.f : 0.f;
            As[ak + s4 * 4 + 2][am] = v.z ? 1.f : 0.f;
            As[ak + s4 * 4 + 3][am] = v.w ? 1.f : 0.f;
        }
        long sb = ((long)b * DIM + n0 + bn) * ND + k0 + bseg * 16;
        us8 h0 = *(const us8*)(thi + sb);
        us8 h1 = *(const us8*)(thi + sb + 8);
        us8 l0 = *(const us8*)(tlo + sb);
        us8 l1 = *(const us8*)(tlo + sb + 8);
        #pragma unroll
        for (int rr2 = 0; rr2 < 8; rr2++) {
            Bs[bseg * 16 + rr2][bn] =
                __uint_as_float((unsigned)h0[rr2] << 16) + __uint_as_float((unsigned)l0[rr2] << 16);
            Bs[bseg * 16 + 8 + rr2][bn] =
                __uint_as_float((unsigned)h1[rr2] << 16) + __uint_as_float((unsigned)l1[rr2] << 16);
        }
        __syncthreads();
        #pragma unroll 8
        for (int kk = 0; kk < 64; kk++) {
            float4 av = *(const float4*)&As[kk][ty * 4];
            float4 bv = *(const float4*)&Bs[kk][tx * 4];
            float a[4] = {av.x, av.y, av.z, av.w};
            float w[4] = {bv.x, bv.y, bv.z, bv.w};
            #pragma unroll
            for (int mi = 0; mi < 4; mi++)
                #pragma unroll
                for (int ni = 0; ni < 4; ni++)
                    acc[mi][ni] += a[mi] * w[ni];
        }
        __syncthreads();
    }
    #pragma unroll
    for (int mi = 0; mi < 4; mi++) {
        int gm = ty * 4 + mi;
        float scv = (msk[b * 64 + gm] != 0) ? 1.f : 0.f;
        float4 o; o.x = scv * acc[mi][0]; o.y = scv * acc[mi][1]; o.z = scv * acc[mi][2]; o.w = scv * acc[mi][3];
        *(float4*)(outp + ((long)b * 64 + gm) * DIM + n0 + tx * 4) = o;
    }
}

// ============ pre_sr = bits @ (hi+lo) via bf16 MFMA, 128x128 tile ============
__global__ __launch_bounds__(256) void k_pre_sr_mfma(
    const unsigned* __restrict__ bits,
    const unsigned short* __restrict__ thi, const unsigned short* __restrict__ tlo,
    float* __restrict__ out)
{
    // XCD-aware swizzle: 1024 tiles, 8 XCDs -> each XCD gets 128 contiguous tiles (2 batches)
    int flat = blockIdx.x;
    int tile = (flat & 7) * 128 + (flat >> 3);
    int b = tile >> 6;
    int m0 = ((tile >> 2) & 15) * 128;
    int n0 = (tile & 3) * 128;

    __shared__ unsigned short Aexp[128 * 64];  // byte = row*128 + k*2, chunk ^= row&7
    __shared__ unsigned short Bhi[128 * 64];   // byte = n*128 + k*2, chunk ^= n&7
    __shared__ unsigned short Blo[128 * 64];

    int tid = threadIdx.x;
    int lane = tid & 63, wid = tid >> 6;
    int wm = wid >> 1, wn = wid & 1;           // 2x2 wave grid, 64x64 per wave

    int arow = tid >> 1, awsel = tid & 1;      // A expansion task: (row, 32-bit word)
    const unsigned* abit_base = bits + ((long)b * ND + m0 + arow) * 64 + awsel;

    f32x4 acc[4][4];
    #pragma unroll
    for (int i = 0; i < 4; i++)
        #pragma unroll
        for (int j = 0; j < 4; j++)
            acc[i][j] = (f32x4){0.f, 0.f, 0.f, 0.f};

    for (int k0 = 0; k0 < ND; k0 += 64) {
        // ---- stage B (hi+lo), reg-staged, swizzled LDS ----
        #pragma unroll
        for (int u = 0; u < 8; u++) {
            int lin = (u & 3) * 256 + tid;     // 0..1023 -> (n, 16B chunk)
            int n = lin >> 3, c = lin & 7;
            const unsigned short* src = (u < 4 ? thi : tlo)
                + ((long)b * DIM + n0 + n) * ND + k0 + c * 8;
            uint4 v = *(const uint4*)src;
            char* dst = (char*)(u < 4 ? Bhi : Blo) + n * 128 + ((c ^ (n & 7)) * 16);
            *(uint4*)dst = v;
        }
        // ---- stage A: load bit word, expand to bf16 {0,1} ----
        {
            unsigned w = abit_base[k0 >> 5];
            char* ab = (char*)Aexp + arow * 128;
            #pragma unroll
            for (int c = 0; c < 4; c++) {
                uint4 q;
                q.x = (((w >> (c * 8 + 0)) & 1u) ? 0x3F80u : 0u) | (((w >> (c * 8 + 1)) & 1u) ? 0x3F800000u : 0u);
                q.y = (((w >> (c * 8 + 2)) & 1u) ? 0x3F80u : 0u) | (((w >> (c * 8 + 3)) & 1u) ? 0x3F800000u : 0u);
                q.z = (((w >> (c * 8 + 4)) & 1u) ? 0x3F80u : 0u) | (((w >> (c * 8 + 5)) & 1u) ? 0x3F800000u : 0u);
                q.w = (((w >> (c * 8 + 6)) & 1u) ? 0x3F80u : 0u) | (((w >> (c * 8 + 7)) & 1u) ? 0x3F800000u : 0u);
                int chunk = (awsel * 4 + c) ^ (arow & 7);
                *(uint4*)(ab + chunk * 16) = q;
            }
        }
        __syncthreads();
        // ---- 2 k-steps of 32, 32 MFMA each (hi + lo into same acc) ----
        #pragma unroll
        for (int ks = 0; ks < 2; ks++) {
            bf16x8 af[4], bh[4], bl[4];
            #pragma unroll
            for (int i = 0; i < 4; i++) {
                int rr = wm * 64 + i * 16 + (lane & 15);
                int cc = (ks * 4 + (lane >> 4)) ^ (rr & 7);
                af[i] = *(bf16x8*)((char*)Aexp + rr * 128 + cc * 16);
                int nn = wn * 64 + i * 16 + (lane & 15);
                int c2 = (ks * 4 + (lane >> 4)) ^ (nn & 7);
                bh[i] = *(bf16x8*)((char*)Bhi + nn * 128 + c2 * 16);
                bl[i] = *(bf16x8*)((char*)Blo + nn * 128 + c2 * 16);
            }
            #pragma unroll
            for (int mi = 0; mi < 4; mi++)
                #pragma unroll
                for (int ni = 0; ni < 4; ni++) {
                    acc[mi][ni] = __builtin_amdgcn_mfma_f32_16x16x32_bf16(af[mi], bh[ni], acc[mi][ni], 0, 0, 0);
                    acc[mi][ni] = __builtin_amdgcn_mfma_f32_16x16x32_bf16(af[mi], bl[ni], acc[mi][ni], 0, 0, 0);
                }
        }
        __syncthreads();
    }
    // ---- epilogue: C mapping col=lane&15, row=(lane>>4)*4+reg ----
    #pragma unroll
    for (int mi = 0; mi < 4; mi++) {
        int grow = m0 + wm * 64 + mi * 16 + (lane >> 4) * 4;
        #pragma unroll
        for (int ni = 0; ni < 4; ni++) {
            int gcol = n0 + wn * 64 + ni * 16 + (lane & 15);
            float* p = out + ((long)b * ND + grow) * DIM + gcol;
            p[0]       = acc[mi][ni][0];
            p[DIM]     = acc[mi][ni][1];
            p[2 * DIM] = acc[mi][ni][2];
            p[3 * DIM] = acc[mi][ni][3];
        }
    }
}

// ============ aggdc = [rel_rd^T | rel_cd^T] (2048 x 128) @ info_rc (128 x 512), dm-masked ============
__global__ __launch_bounds__(256) void k_aggdc(
    const int* __restrict__ rel_rd, const int* __restrict__ rel_cd,
    const float* __restrict__ info_rc, const int* __restrict__ dmask,
    float* __restrict__ out)
{
    int b = blockIdx.z, m0 = blockIdx.y * 128, n0 = blockIdx.x * 128;
    __shared__ float As[32][132], Bs[32][132];
    float acc[8][8] = {};
    int tx = threadIdx.x & 15, ty = threadIdx.x >> 4;
    int ak = threadIdx.x >> 3, aj = (threadIdx.x & 7) * 16;
    for (int kt = 0; kt < 4; kt++) {
        const int* rel = (kt < 2) ? rel_rd : rel_cd;
        int krow = (kt & 1) * 32 + ak;
        const int4* pa = (const int4*)(rel + ((long)b * 64 + krow) * ND + m0 + aj);
        #pragma unroll
        for (int s = 0; s < 4; s++) {
            int4 v = pa[s];
            float4 f; f.x = v.x ? 1.f : 0.f; f.y = v.y ? 1.f : 0.f; f.z = v.z ? 1.f : 0.f; f.w = v.w ? 1.f : 0.f;
            *(float4*)&As[ak][aj + s * 4] = f;
        }
        const float4* pb = (const float4*)(info_rc + ((long)b * 128 + kt * 32 + ak) * DIM + n0 + aj);
        #pragma unroll
        for (int s = 0; s < 4; s++) *(float4*)&Bs[ak][aj + s * 4] = pb[s];
        __syncthreads();
        #pragma unroll 4
        for (int kk = 0; kk < 32; kk++) {
            float4 a0 = *(const float4*)&As[kk][ty * 8];
            float4 a1 = *(const float4*)&As[kk][ty * 8 + 4];
            float4 b0 = *(const float4*)&Bs[kk][tx * 8];
            float4 b1 = *(const float4*)&Bs[kk][tx * 8 + 4];
            float a[8] = {a0.x, a0.y, a0.z, a0.w, a1.x, a1.y, a1.z, a1.w};
            float w[8] = {b0.x, b0.y, b0.z, b0.w, b1.x, b1.y, b1.z, b1.w};
            #pragma unroll
            for (int mi = 0; mi < 8; mi++)
                #pragma unroll
                for (int ni = 0; ni < 8; ni++)
                    acc[mi][ni] += a[mi] * w[ni];
        }
        __syncthreads();
    }
    #pragma unroll
    for (int mi = 0; mi < 8; mi++) {
        int gm = m0 + ty * 8 + mi;
        float mq = (dmask[(long)b * ND + gm] != 0) ? 1.f : 0.f;
        float* po = out + ((long)b * ND + gm) * DIM + n0 + tx * 8;
        float4 o0; o0.x = mq * acc[mi][0]; o0.y = mq * acc[mi][1]; o0.z = mq * acc[mi][2]; o0.w = mq * acc[mi][3];
        float4 o1; o1.x = mq * acc[mi][4]; o1.y = mq * acc[mi][5]; o1.z = mq * acc[mi][6]; o1.w = mq * acc[mi][7];
        *(float4*)(po) = o0; *(float4*)(po + 4) = o1;
    }
}

// ============ dc projection + combine: out = relu((pre_sr @ W_sr^T + aggdc) / dc_num) ============
__global__ __launch_bounds__(256) void k_proj_dc(
    const float* __restrict__ A, const float* __restrict__ W,
    const float* __restrict__ addm, const float* __restrict__ rownum,
    float* __restrict__ out)
{
    int b = blockIdx.z, m0 = blockIdx.y * 128, n0 = blockIdx.x * 128;
    __shared__ float As[32][132], Ws2[32][132];
    float acc[8][8] = {};
    int tx = threadIdx.x & 15, ty = threadIdx.x >> 4;
    int am = threadIdx.x >> 1, ah = (threadIdx.x & 1) * 16;
    for (int k0 = 0; k0 < DIM; k0 += 32) {
        const float4* pa = (const float4*)(A + ((long)b * ND + m0 + am) * DIM + k0 + ah);
        float4 v0 = pa[0], v1 = pa[1], v2 = pa[2], v3 = pa[3];
        As[ah + 0][am] = v0.x;  As[ah + 1][am] = v0.y;  As[ah + 2][am] = v0.z;  As[ah + 3][am] = v0.w;
        As[ah + 4][am] = v1.x;  As[ah + 5][am] = v1.y;  As[ah + 6][am] = v1.z;  As[ah + 7][am] = v1.w;
        As[ah + 8][am] = v2.x;  As[ah + 9][am] = v2.y;  As[ah + 10][am] = v2.z; As[ah + 11][am] = v2.w;
        As[ah + 12][am] = v3.x; As[ah + 13][am] = v3.y; As[ah + 14][am] = v3.z; As[ah + 15][am] = v3.w;
        const float4* pw = (const float4*)(W + (long)(n0 + am) * DIM + k0 + ah);
        v0 = pw[0]; v1 = pw[1]; v2 = pw[2]; v3 = pw[3];
        Ws2[ah + 0][am] = v0.x;  Ws2[ah + 1][am] = v0.y;  Ws2[ah + 2][am] = v0.z;  Ws2[ah + 3][am] = v0.w;
        Ws2[ah + 4][am] = v1.x;  Ws2[ah + 5][am] = v1.y;  Ws2[ah + 6][am] = v1.z;  Ws2[ah + 7][am] = v1.w;
        Ws2[ah + 8][am] = v2.x;  Ws2[ah + 9][am] = v2.y;  Ws2[ah + 10][am] = v2.z; Ws2[ah + 11][am] = v2.w;
        Ws2[ah + 12][am] = v3.x; Ws2[ah + 13][am] = v3.y; Ws2[ah + 14][am] = v3.z; Ws2[ah + 15][am] = v3.w;
        __syncthreads();
        #pragma unroll 4
        for (int kk = 0; kk < 32; kk++) {
            float4 a0 = *(const float4*)&As[kk][ty * 8];
            float4 a1 = *(const float4*)&As[kk][ty * 8 + 4];
            float4 b0 = *(const float4*)&Ws2[kk][tx * 8];
            float4 b1 = *(const float4*)&Ws2[kk][tx * 8 + 4];
            float a[8] = {a0.x, a0.y, a0.z, a0.w, a1.x, a1.y, a1.z, a1.w};
            float w[8] = {b0.x, b0.y, b0.z, b0.w, b1.x, b1.y, b1.z, b1.w};
            #pragma unroll
            for (int mi = 0; mi < 8; mi++)
                #pragma unroll
                for (int ni = 0; ni < 8; ni++)
                    acc[mi][ni] += a[mi] * w[ni];
        }
        __syncthreads();
    }
    #pragma unroll
    for (int mi = 0; mi < 8; mi++) {
        int gm = m0 + ty * 8 + mi;
        float inv = 1.f / rownum[(long)b * ND + gm];
        const float4* pad = (const float4*)(addm + ((long)b * ND + gm) * DIM + n0 + tx * 8);
        float4 d0 = pad[0], d1 = pad[1];
        float* po = out + ((long)b * ND + gm) * DIM + n0 + tx * 8;
        float4 o0, o1;
        o0.x = fmaxf((acc[mi][0] + d0.x) * inv, 0.f);
        o0.y = fmaxf((acc[mi][1] + d0.y) * inv, 0.f);
        o0.z = fmaxf((acc[mi][2] + d0.z) * inv, 0.f);
        o0.w = fmaxf((acc[mi][3] + d0.w) * inv, 0.f);
        o1.x = fmaxf((acc[mi][4] + d1.x) * inv, 0.f);
        o1.y = fmaxf((acc[mi][5] + d1.y) * inv, 0.f);
        o1.z = fmaxf((acc[mi][6] + d1.z) * inv, 0.f);
        o1.w = fmaxf((acc[mi][7] + d1.w) * inv, 0.f);
        *(float4*)(po) = o0; *(float4*)(po + 4) = o1;
    }
}

// ==================================================================================
extern "C" void kernel_launch(void* const* d_in, const int* in_sizes, int n_in,
                              void* d_out, int out_size, void* d_ws, size_t ws_size,
                              hipStream_t stream)
{
    const float* q       = (const float*)d_in[0];
    const float* rh0     = (const float*)d_in[1];
    const float* ch0     = (const float*)d_in[2];
    const float* dc0     = (const float*)d_in[3];
    const int*   rm      = (const int*)d_in[4];
    const int*   cm      = (const int*)d_in[5];
    const int*   dmask   = (const int*)d_in[6];
    const int*   same_row= (const int*)d_in[7];
    const int*   same_col= (const int*)d_in[8];
    const int*   rel_rd  = (const int*)d_in[9];
    const int*   rel_cd  = (const int*)d_in[10];
    const float* wnode   = (const float*)d_in[11];
    const float* w_rdc   = (const float*)d_in[12];
    const float* w_cdc   = (const float*)d_in[13];
    const float* w_dcr   = (const float*)d_in[14];
    const float* w_dcc   = (const float*)d_in[15];
    const float* w_sr    = (const float*)d_in[16];
    const float* w_rq    = (const float*)d_in[18];
    const float* w_cq    = (const float*)d_in[19];

    float* out = (float*)d_out;
    float* rh = out;                           // [16,64,512]
    float* ch = out + (long)NB * NR * DIM;     // [16,64,512]
    float* dc = out + (long)NB * NR * DIM * 2; // [16,2048,512]

    if (ws_size < (size_t)WS_FLOATS * 4) return;

    float* ws      = (float*)d_ws;
    float* rh_num  = ws + OFF_RHNUM;
    float* ch_num  = ws + OFF_CHNUM;
    float* dc_num  = ws + OFF_DCNUM;
    float* rh_w    = ws + OFF_RHW;
    float* ch_w    = ws + OFF_CHW;
    float* qrow    = ws + OFF_QROW;
    float* qcol    = ws + OFF_QCOL;
    float* pre_r   = ws + OFF_PRER;
    float* pre_c   = ws + OFF_PREC;
    float* info_rc = ws + OFF_INFORC;
    unsigned* bits = (unsigned*)(ws + OFF_BITS);
    unsigned short* thi = (unsigned short*)(ws + OFF_DCS);
    unsigned short* tlo = thi + (size_t)NB * DIM * ND;   // 33.5 MB each
    float* aggdc   = ws + OFF_DCS;             // alias: planes dead before k_aggdc writes
    float* pre_sr  = ws + OFF_PRESR;

    hipMemcpyAsync(rh, rh0, sizeof(float) * (size_t)NB * NR * DIM, hipMemcpyDeviceToDevice, stream);
    hipMemcpyAsync(ch, ch0, sizeof(float) * (size_t)NB * NCOL * DIM, hipMemcpyDeviceToDevice, stream);
    hipMemcpyAsync(dc, dc0, sizeof(float) * (size_t)NB * ND * DIM, hipMemcpyDeviceToDevice, stream);

    k_bits<<<NB * ND, 256, 0, stream>>>(same_row, same_col, dmask, bits, dc_num);
    k_rcnum<<<512, 256, 0, stream>>>(rel_rd, rel_cd, rm, cm, dmask, rh_num, ch_num);
    k_dcnum_final<<<dim3(ND / 256, NB), 256, 0, stream>>>(rel_rd, rel_cd, rm, cm, dmask, dc_num);
    k_q<<<dim3(128, 2, NB), 256, 0, stream>>>(q, w_rq, w_cq, qrow, qcol);

    for (int it = 0; it < 2; it++) {
        k_gate_rc<<<512, 256, 0, stream>>>(rh, ch, rm, cm, wnode, rh_w, ch_w);
        k_split_t<<<dim3(128, NB), 256, 0, stream>>>(dc, wnode, dmask, thi, tlo);
        gemm_small<1><<<dim3(8, 1, NB), 256, 0, stream>>>(rh, (long)NR * DIM, w_dcr,
            info_rc, 128L * DIM, rh_w, 1.0f, nullptr, nullptr, nullptr, NR);
        gemm_small<1><<<dim3(8, 1, NB), 256, 0, stream>>>(ch, (long)NCOL * DIM, w_dcc,
            info_rc + 64L * DIM, 128L * DIM, ch_w, 2.0f, nullptr, nullptr, nullptr, NCOL);
        k_pre_sr_mfma<<<1024, 256, 0, stream>>>(bits, thi, tlo, pre_sr);
        k_pre_rc<<<dim3(8, 2, NB), 256, 0, stream>>>(rel_rd, rel_cd, thi, tlo, rm, cm, pre_r, pre_c);
        k_aggdc<<<dim3(4, 16, NB), 256, 0, stream>>>(rel_rd, rel_cd, info_rc, dmask, aggdc);
        gemm_small<2><<<dim3(8, 1, NB), 256, 0, stream>>>(pre_r, (long)NR * DIM, w_rdc,
            rh, (long)NR * DIM, nullptr, 1.0f, rm, qrow, rh_num, NR);
        gemm_small<2><<<dim3(8, 1, NB), 256, 0, stream>>>(pre_c, (long)NCOL * DIM, w_cdc,
            ch, (long)NCOL * DIM, nullptr, 1.0f, cm, qcol, ch_num, NCOL);
        k_proj_dc<<<dim3(4, 16, NB), 256, 0, stream>>>(pre_sr, w_sr, aggdc, dc_num, dc);
    }
}

// Round 3
// 1156.589 us; speedup vs baseline: 2.1234x; 1.2738x over previous
//
#include <hip/hip_runtime.h>
#include <math.h>

#define NB 16
#define NR 64
#define NCOL 64
#define ND 2048
#define DIM 512

typedef __attribute__((ext_vector_type(4))) float f32x4;
typedef __attribute__((ext_vector_type(8))) short bf16x8;
typedef __attribute__((ext_vector_type(8))) unsigned short us8;

// ---------------- workspace layout (float offsets) ----------------
#define OFF_RHNUM  0L
#define OFF_CHNUM  1024L
#define OFF_DCNUM  2048L
#define OFF_RHW    34816L
#define OFF_CHW    35840L
#define OFF_QROW   36864L
#define OFF_QCOL   45056L
#define OFF_PRER   53248L     // pre_r; whi/wlo alias its first 131072 floats (dead window)
#define OFF_PREC   577536L
#define OFF_INFORC 1101824L
#define OFF_BITS   2150400L
#define OFF_DCS    4247552L   // dhi/dlo row-major planes; later aliased as aggdc
#define OFF_PROJ   21024768L  // phi/plo transposed proj planes
#define WS_FLOATS  37801984L  // 151.2 MB (unchanged)

// RNE fp32 -> bf16 split: v ~= hi + lo, both bf16
__device__ inline void bsplit(float v, unsigned short& h, unsigned short& l) {
    unsigned uv = __float_as_uint(v);
    unsigned hb = (uv + 0x7FFFu + ((uv >> 16) & 1u)) >> 16;
    h = (unsigned short)hb;
    float lo = v - __uint_as_float(hb << 16);
    unsigned lv = __float_as_uint(lo);
    l = (unsigned short)((lv + 0x7FFFu + ((lv >> 16) & 1u)) >> 16);
}

// ============ gate for rh/ch rows ============
__global__ __launch_bounds__(256) void k_gate_rc(
    const float* __restrict__ rh, const float* __restrict__ ch,
    const int* __restrict__ rm, const int* __restrict__ cm,
    const float* __restrict__ wnode,
    float* __restrict__ rh_w, float* __restrict__ ch_w)
{
    int wave = threadIdx.x >> 6, lane = threadIdx.x & 63;
    int idx = blockIdx.x * 4 + wave;   // < 2048
    const float* xrow; float* outw; int mval;
    if (idx < NB * NR) {
        int b = idx >> 6, r = idx & 63;
        xrow = rh + ((long)b * NR + r) * DIM; mval = rm[b * NR + r]; outw = rh_w + b * NR + r;
    } else {
        int tt = idx - NB * NR; int b = tt >> 6, c = tt & 63;
        xrow = ch + ((long)b * NCOL + c) * DIM; mval = cm[b * NCOL + c]; outw = ch_w + b * NCOL + c;
    }
    const float4* px = (const float4*)xrow;
    const float4* pw = (const float4*)wnode;
    float4 xa = px[lane * 2], xb = px[lane * 2 + 1];
    float4 wa = pw[lane * 2], wb = pw[lane * 2 + 1];
    float s = xa.x * wa.x + xa.y * wa.y + xa.z * wa.z + xa.w * wa.w
            + xb.x * wb.x + xb.y * wb.y + xb.z * wb.z + xb.w * wb.w;
    #pragma unroll
    for (int o = 32; o > 0; o >>= 1) s += __shfl_xor(s, o, 64);
    if (lane == 0) {
        float g = 1.f / (1.f + expf(-s));
        *outw = mval ? g : 0.f;
    }
}

// ============ gate+split dc -> dhi/dlo ROW-MAJOR [b][2048][512] bf16 ============
__global__ __launch_bounds__(256) void k_split(
    const float* __restrict__ src, const float* __restrict__ wnode, const int* __restrict__ dmask,
    unsigned short* __restrict__ dhi, unsigned short* __restrict__ dlo)
{
    int wave = threadIdx.x >> 6, lane = threadIdx.x & 63;
    long idx = (long)blockIdx.x * 4 + wave;          // b*2048 + j
    const float* row = src + idx * DIM;
    const float4* px = (const float4*)row;
    const float4* pw = (const float4*)wnode;
    float4 xa = px[lane * 2], xb = px[lane * 2 + 1];
    float4 wa = pw[lane * 2], wb = pw[lane * 2 + 1];
    float s = xa.x * wa.x + xa.y * wa.y + xa.z * wa.z + xa.w * wa.w
            + xb.x * wb.x + xb.y * wb.y + xb.z * wb.z + xb.w * wb.w;
    #pragma unroll
    for (int o = 32; o > 0; o >>= 1) s += __shfl_xor(s, o, 64);
    float g = 1.f / (1.f + expf(-s));
    float sc = (dmask[idx] != 0) ? g : 0.f;
    float v[8] = {sc * xa.x, sc * xa.y, sc * xa.z, sc * xa.w,
                  sc * xb.x, sc * xb.y, sc * xb.z, sc * xb.w};
    us8 ph, pl;
    #pragma unroll
    for (int i = 0; i < 8; i++) {
        unsigned short hh, ll; bsplit(v[i], hh, ll);
        ph[i] = hh; pl[i] = ll;
    }
    *(us8*)(dhi + idx * DIM + lane * 8) = ph;
    *(us8*)(dlo + idx * DIM + lane * 8) = pl;
}

// ============ split w_sr -> whi/wlo bf16 [512][512] (per iter, aliases pre_r) ============
__global__ __launch_bounds__(256) void k_wsplit(
    const float* __restrict__ w, unsigned short* __restrict__ whi, unsigned short* __restrict__ wlo)
{
    long i = ((long)blockIdx.x * 256 + threadIdx.x) * 8;
    float4 a = *(const float4*)(w + i), b4 = *(const float4*)(w + i + 4);
    float v[8] = {a.x, a.y, a.z, a.w, b4.x, b4.y, b4.z, b4.w};
    us8 ph, pl;
    #pragma unroll
    for (int t = 0; t < 8; t++) {
        unsigned short hh, ll; bsplit(v[t], hh, ll);
        ph[t] = hh; pl[t] = ll;
    }
    *(us8*)(whi + i) = ph;
    *(us8*)(wlo + i) = pl;
}

// ============ q projections (once) ============
__global__ __launch_bounds__(256) void k_q(
    const float* __restrict__ q, const float* __restrict__ wrq, const float* __restrict__ wcq,
    float* __restrict__ qrow, float* __restrict__ qcol)
{
    int b = blockIdx.z;
    const float* W = blockIdx.y ? wcq : wrq;
    float* out = blockIdx.y ? qcol : qrow;
    int wave = threadIdx.x >> 6, lane = threadIdx.x & 63;
    int n = blockIdx.x * 4 + wave;
    const float4* qp = (const float4*)(q + (long)b * DIM);
    const float4* wp = (const float4*)(W + (long)n * DIM);
    float4 a0 = qp[lane * 2], a1 = qp[lane * 2 + 1];
    float4 w0 = wp[lane * 2], w1 = wp[lane * 2 + 1];
    float s = a0.x * w0.x + a0.y * w0.y + a0.z * w0.z + a0.w * w0.w
            + a1.x * w1.x + a1.y * w1.y + a1.z * w1.z + a1.w * w1.w;
    #pragma unroll
    for (int o = 32; o > 0; o >>= 1) s += __shfl_xor(s, o, 64);
    if (lane == 0) out[(long)b * DIM + n] = s;
}

// ============ pack same_row bits + partial dc_num ============
__global__ __launch_bounds__(256) void k_bits(
    const int* __restrict__ sr, const int* __restrict__ sc, const int* __restrict__ dmask,
    unsigned* __restrict__ bits, float* __restrict__ dcnum)
{
    long bi = blockIdx.x;                    // = b*ND + i
    int b = (int)(bi >> 11);
    const int* dmb = dmask + (long)b * ND;
    int dmi = dmb[bi & 2047];
    int wave = threadIdx.x >> 6, lane = threadIdx.x & 63;
    const int* srrow = sr + bi * ND;
    const int* scrow = sc + bi * ND;
    unsigned* brow = bits + bi * 64;
    int cnt = 0;
    for (int rr = 0; rr < 8; rr++) {
        int j = wave * 512 + rr * 64 + lane;
        int dmj = dmb[j] != 0;
        bool p1 = dmi && dmj && (srrow[j] != 0);
        unsigned long long m1 = __ballot(p1);
        bool p2 = dmi && dmj && (scrow[j] != 0);
        unsigned long long m2 = __ballot(p2);
        if (lane == 0) {
            int w0 = wave * 16 + rr * 2;
            brow[w0] = (unsigned)m1; brow[w0 + 1] = (unsigned)(m1 >> 32);
        }
        cnt += __popcll(m1) + __popcll(m2);
    }
    __shared__ int red[4];
    if (lane == 0) red[wave] = cnt;
    __syncthreads();
    if (threadIdx.x == 0) dcnum[bi] = (float)(red[0] + red[1] + red[2] + red[3]);
}

// ============ rh_num / ch_num ============
__global__ __launch_bounds__(256) void k_rcnum(
    const int* __restrict__ rel_rd, const int* __restrict__ rel_cd,
    const int* __restrict__ rm, const int* __restrict__ cm, const int* __restrict__ dmask,
    float* __restrict__ rh_num, float* __restrict__ ch_num)
{
    int wave = threadIdx.x >> 6, lane = threadIdx.x & 63;
    long idx = (long)blockIdx.x * 4 + wave;  // < 2048
    const int* row; int mval; float* out; const int* dmb;
    if (idx < NB * NR) {
        int b = (int)(idx >> 6), r = (int)(idx & 63);
        row = rel_rd + ((long)b * NR + r) * ND; mval = rm[b * NR + r];
        out = rh_num + b * NR + r; dmb = dmask + (long)b * ND;
    } else {
        long tt = idx - NB * NR; int b = (int)(tt >> 6), c = (int)(tt & 63);
        row = rel_cd + ((long)b * NCOL + c) * ND; mval = cm[b * NCOL + c];
        out = ch_num + b * NCOL + c; dmb = dmask + (long)b * ND;
    }
    int cnt = 0;
    for (int rr = 0; rr < 32; rr++) {
        int j = rr * 64 + lane;
        cnt += (row[j] != 0 && dmb[j] != 0) ? 1 : 0;
    }
    #pragma unroll
    for (int o = 32; o > 0; o >>= 1) cnt += __shfl_xor(cnt, o, 64);
    if (lane == 0) {
        float s = mval ? (float)cnt : 0.f;
        *out = (s >= 1.f) ? (s + 1.f) : 1.f;
    }
}

// ============ finalize dc_num ============
__global__ __launch_bounds__(256) void k_dcnum_final(
    const int* __restrict__ rel_rd, const int* __restrict__ rel_cd,
    const int* __restrict__ rm, const int* __restrict__ cm, const int* __restrict__ dmask,
    float* __restrict__ dcnum)
{
    int b = blockIdx.y;
    int j = blockIdx.x * 256 + threadIdx.x;
    const int* rd = rel_rd + (long)b * NR * ND;
    const int* cd = rel_cd + (long)b * NCOL * ND;
    const int* rmb = rm + b * NR;
    const int* cmb = cm + b * NCOL;
    int cnt = 0;
    for (int r = 0; r < NR; r++)  cnt += (rd[(long)r * ND + j] != 0 && rmb[r] != 0) ? 1 : 0;
    for (int c = 0; c < NCOL; c++) cnt += (cd[(long)c * ND + j] != 0 && cmb[c] != 0) ? 1 : 0;
    float add = (dmask[(long)b * ND + j] != 0) ? (float)cnt : 0.f;
    float tv = dcnum[(long)b * ND + j] + add;
    dcnum[(long)b * ND + j] = (tv >= 1.f) ? tv : 1.f;
}

// ============ small dense GEMM: M=64, N=K=512 ============
template<int EPI>
__global__ __launch_bounds__(256) void gemm_small(
    const float* __restrict__ A, long sA,
    const float* __restrict__ W,
    float* __restrict__ C, long sC,
    const float* __restrict__ rowscale, float alpha,
    const int* __restrict__ mrow, const float* __restrict__ addvec,
    const float* __restrict__ rownum, int rsb)
{
    int b = blockIdx.z;
    int n0 = blockIdx.x * 64;
    __shared__ float As[32][68], Ws[32][68];
    float acc[4][4] = {};
    int tx = threadIdx.x & 15, ty = threadIdx.x >> 4;
    int lm = threadIdx.x >> 2, lk = (threadIdx.x & 3) * 8;
    const float* Ab = A + (long)b * sA;
    for (int k0 = 0; k0 < DIM; k0 += 32) {
        const float4* pa = (const float4*)(Ab + (long)lm * DIM + k0 + lk);
        float4 va0 = pa[0], va1 = pa[1];
        const float4* pw = (const float4*)(W + (long)(n0 + lm) * DIM + k0 + lk);
        float4 vw0 = pw[0], vw1 = pw[1];
        As[lk + 0][lm] = va0.x; As[lk + 1][lm] = va0.y; As[lk + 2][lm] = va0.z; As[lk + 3][lm] = va0.w;
        As[lk + 4][lm] = va1.x; As[lk + 5][lm] = va1.y; As[lk + 6][lm] = va1.z; As[lk + 7][lm] = va1.w;
        Ws[lk + 0][lm] = vw0.x; Ws[lk + 1][lm] = vw0.y; Ws[lk + 2][lm] = vw0.z; Ws[lk + 3][lm] = vw0.w;
        Ws[lk + 4][lm] = vw1.x; Ws[lk + 5][lm] = vw1.y; Ws[lk + 6][lm] = vw1.z; Ws[lk + 7][lm] = vw1.w;
        __syncthreads();
        #pragma unroll
        for (int kk = 0; kk < 32; kk++) {
            float4 av = *(const float4*)&As[kk][ty * 4];
            float4 wv = *(const float4*)&Ws[kk][tx * 4];
            float a[4] = {av.x, av.y, av.z, av.w};
            float w[4] = {wv.x, wv.y, wv.z, wv.w};
            #pragma unroll
            for (int mi = 0; mi < 4; mi++)
                #pragma unroll
                for (int ni = 0; ni < 4; ni++)
                    acc[mi][ni] += a[mi] * w[ni];
        }
        __syncthreads();
    }
    #pragma unroll
    for (int mi = 0; mi < 4; mi++) {
        int gm = ty * 4 + mi;
        float vals[4];
        if (EPI == 1) {
            float scv = alpha * rowscale[(long)b * rsb + gm];
            #pragma unroll
            for (int ni = 0; ni < 4; ni++) vals[ni] = scv * acc[mi][ni];
        } else {
            float mq = (mrow[(long)b * rsb + gm] != 0) ? 1.f : 0.f;
            float inv = 1.f / rownum[(long)b * rsb + gm];
            #pragma unroll
            for (int ni = 0; ni < 4; ni++) {
                float tv = (acc[mi][ni] + mq * addvec[(long)b * DIM + n0 + tx * 4 + ni]) * inv;
                vals[ni] = fmaxf(tv, 0.f);
            }
        }
        float4 o; o.x = vals[0]; o.y = vals[1]; o.z = vals[2]; o.w = vals[3];
        *(float4*)(C + (long)b * sC + (long)gm * DIM + n0 + tx * 4) = o;
    }
}

// ============ projT = Wsr-split @ dcs-split^T via MFMA -> bf16 hi/lo planes [b][512][2048] ============
__global__ __launch_bounds__(256) void k_proj_mfma(
    const unsigned short* __restrict__ whi, const unsigned short* __restrict__ wlo,
    const unsigned short* __restrict__ dhi, const unsigned short* __restrict__ dlo,
    unsigned short* __restrict__ phi, unsigned short* __restrict__ plo)
{
    int flat = blockIdx.x;                   // 1024 blocks
    int tile = (flat & 7) * 128 + (flat >> 3);
    int b = tile >> 6;
    int rem = tile & 63;
    int m0 = (rem >> 4) * 128;               // W-row tile (4)
    int n0 = (rem & 15) * 128;               // cell tile (16)

    __shared__ unsigned short Ahi[128 * 64], Alo[128 * 64];
    __shared__ unsigned short Bhi[128 * 64], Blo[128 * 64];

    int tid = threadIdx.x;
    int lane = tid & 63, wid = tid >> 6;
    int wm = wid >> 1, wn = wid & 1;

    int srow = tid >> 1, sseg = tid & 1;     // staging: (row, 32-k half)

    f32x4 acc[4][4];
    #pragma unroll
    for (int i = 0; i < 4; i++)
        #pragma unroll
        for (int j = 0; j < 4; j++)
            acc[i][j] = (f32x4){0.f, 0.f, 0.f, 0.f};

    for (int k0 = 0; k0 < DIM; k0 += 64) {
        // stage A from whi/wlo  (rows = W rows m0+srow, 32 k's per thread)
        {
            const uint4* ph = (const uint4*)(whi + (long)(m0 + srow) * DIM + k0 + sseg * 32);
            const uint4* pl = (const uint4*)(wlo + (long)(m0 + srow) * DIM + k0 + sseg * 32);
            #pragma unroll
            for (int s = 0; s < 4; s++) {
                int c = (sseg * 4 + s) ^ (srow & 7);
                *(uint4*)((char*)Ahi + srow * 128 + c * 16) = ph[s];
                *(uint4*)((char*)Alo + srow * 128 + c * 16) = pl[s];
            }
        }
        // stage B from dhi/dlo  (rows = cells n0+srow)
        {
            const uint4* ph = (const uint4*)(dhi + ((long)b * ND + n0 + srow) * DIM + k0 + sseg * 32);
            const uint4* pl = (const uint4*)(dlo + ((long)b * ND + n0 + srow) * DIM + k0 + sseg * 32);
            #pragma unroll
            for (int s = 0; s < 4; s++) {
                int c = (sseg * 4 + s) ^ (srow & 7);
                *(uint4*)((char*)Bhi + srow * 128 + c * 16) = ph[s];
                *(uint4*)((char*)Blo + srow * 128 + c * 16) = pl[s];
            }
        }
        __syncthreads();
        #pragma unroll
        for (int ks = 0; ks < 2; ks++) {
            bf16x8 ah[4], al[4], bh[4], bl[4];
            #pragma unroll
            for (int i = 0; i < 4; i++) {
                int rr = wm * 64 + i * 16 + (lane & 15);
                int cc = (ks * 4 + (lane >> 4)) ^ (rr & 7);
                ah[i] = *(bf16x8*)((char*)Ahi + rr * 128 + cc * 16);
                al[i] = *(bf16x8*)((char*)Alo + rr * 128 + cc * 16);
                int nn = wn * 64 + i * 16 + (lane & 15);
                int c2 = (ks * 4 + (lane >> 4)) ^ (nn & 7);
                bh[i] = *(bf16x8*)((char*)Bhi + nn * 128 + c2 * 16);
                bl[i] = *(bf16x8*)((char*)Blo + nn * 128 + c2 * 16);
            }
            #pragma unroll
            for (int mi = 0; mi < 4; mi++)
                #pragma unroll
                for (int ni = 0; ni < 4; ni++) {
                    acc[mi][ni] = __builtin_amdgcn_mfma_f32_16x16x32_bf16(ah[mi], bh[ni], acc[mi][ni], 0, 0, 0);
                    acc[mi][ni] = __builtin_amdgcn_mfma_f32_16x16x32_bf16(ah[mi], bl[ni], acc[mi][ni], 0, 0, 0);
                    acc[mi][ni] = __builtin_amdgcn_mfma_f32_16x16x32_bf16(al[mi], bh[ni], acc[mi][ni], 0, 0, 0);
                }
        }
        __syncthreads();
    }
    // epilogue: split acc -> phi/plo at [b][n=W-row][j=cell]
    #pragma unroll
    for (int mi = 0; mi < 4; mi++) {
        int grow = m0 + wm * 64 + mi * 16 + (lane >> 4) * 4;
        #pragma unroll
        for (int ni = 0; ni < 4; ni++) {
            int gcol = n0 + wn * 64 + ni * 16 + (lane & 15);
            #pragma unroll
            for (int r = 0; r < 4; r++) {
                unsigned short hh, ll; bsplit(acc[mi][ni][r], hh, ll);
                long off = ((long)b * DIM + grow + r) * ND + gcol;
                phi[off] = hh; plo[off] = ll;
            }
        }
    }
}

// ============ pre_r / pre_c: rel @ (dhi+dlo) row-major planes ============
__global__ __launch_bounds__(256) void k_pre_rc(
    const int* __restrict__ rel_rd, const int* __restrict__ rel_cd,
    const unsigned short* __restrict__ dhi, const unsigned short* __restrict__ dlo,
    const int* __restrict__ rm, const int* __restrict__ cm,
    float* __restrict__ pre_r, float* __restrict__ pre_c)
{
    int b = blockIdx.z, n0 = blockIdx.x * 64;
    const int* rel = blockIdx.y ? rel_cd : rel_rd;
    const int* msk = blockIdx.y ? cm : rm;
    float* outp = blockIdx.y ? pre_c : pre_r;
    __shared__ float As[64][68], Bs[64][68];
    float acc[4][4] = {};
    int tx = threadIdx.x & 15, ty = threadIdx.x >> 4;
    int am = threadIdx.x >> 2, ak = (threadIdx.x & 3) * 16;
    int bj = threadIdx.x >> 2, bseg = threadIdx.x & 3;
    for (int k0 = 0; k0 < ND; k0 += 64) {
        const int4* pa = (const int4*)(rel + ((long)b * 64 + am) * ND + k0 + ak);
        #pragma unroll
        for (int s4 = 0; s4 < 4; s4++) {
            int4 v = pa[s4];
            As[ak + s4 * 4 + 0][am] = v.x ? 1.f : 0.f;
            As[ak + s4 * 4 + 1][am] = v.y ? 1.f : 0.f;
            As[ak + s4 * 4 + 2][am] = v.z ? 1.f : 0.f;
            As[ak + s4 * 4 + 3][am] = v.w ? 1.f : 0.f;
        }
        long sb = ((long)b * ND + k0 + bj) * DIM + n0 + bseg * 16;
        us8 h0 = *(const us8*)(dhi + sb);
        us8 h1 = *(const us8*)(dhi + sb + 8);
        us8 l0 = *(const us8*)(dlo + sb);
        us8 l1 = *(const us8*)(dlo + sb + 8);
        #pragma unroll
        for (int t = 0; t < 8; t++) {
            Bs[bj][bseg * 16 + t] =
                __uint_as_float((unsigned)h0[t] << 16) + __uint_as_float((unsigned)l0[t] << 16);
            Bs[bj][bseg * 16 + 8 + t] =
                __uint_as_float((unsigned)h1[t] << 16) + __uint_as_float((unsigned)l1[t] << 16);
        }
        __syncthreads();
        #pragma unroll 8
        for (int kk = 0; kk < 64; kk++) {
            float4 av = *(const float4*)&As[kk][ty * 4];
            float4 bv = *(const float4*)&Bs[kk][tx * 4];
            float a[4] = {av.x, av.y, av.z, av.w};
            float w[4] = {bv.x, bv.y, bv.z, bv.w};
            #pragma unroll
            for (int mi = 0; mi < 4; mi++)
                #pragma unroll
                for (int ni = 0; ni < 4; ni++)
                    acc[mi][ni] += a[mi] * w[ni];
        }
        __syncthreads();
    }
    #pragma unroll
    for (int mi = 0; mi < 4; mi++) {
        int gm = ty * 4 + mi;
        float scv = (msk[b * 64 + gm] != 0) ? 1.f : 0.f;
        float4 o; o.x = scv * acc[mi][0]; o.y = scv * acc[mi][1]; o.z = scv * acc[mi][2]; o.w = scv * acc[mi][3];
        *(float4*)(outp + ((long)b * 64 + gm) * DIM + n0 + tx * 4) = o;
    }
}

// ============ aggdc = [rel_rd^T | rel_cd^T] @ info_rc, dm-masked ============
__global__ __launch_bounds__(256) void k_aggdc(
    const int* __restrict__ rel_rd, const int* __restrict__ rel_cd,
    const float* __restrict__ info_rc, const int* __restrict__ dmask,
    float* __restrict__ out)
{
    int b = blockIdx.z, m0 = blockIdx.y * 128, n0 = blockIdx.x * 128;
    __shared__ float As[32][132], Bs[32][132];
    float acc[8][8] = {};
    int tx = threadIdx.x & 15, ty = threadIdx.x >> 4;
    int ak = threadIdx.x >> 3, aj = (threadIdx.x & 7) * 16;
    for (int kt = 0; kt < 4; kt++) {
        const int* rel = (kt < 2) ? rel_rd : rel_cd;
        int krow = (kt & 1) * 32 + ak;
        const int4* pa = (const int4*)(rel + ((long)b * 64 + krow) * ND + m0 + aj);
        #pragma unroll
        for (int s = 0; s < 4; s++) {
            int4 v = pa[s];
            float4 f; f.x = v.x ? 1.f : 0.f; f.y = v.y ? 1.f : 0.f; f.z = v.z ? 1.f : 0.f; f.w = v.w ? 1.f : 0.f;
            *(float4*)&As[ak][aj + s * 4] = f;
        }
        const float4* pb = (const float4*)(info_rc + ((long)b * 128 + kt * 32 + ak) * DIM + n0 + aj);
        #pragma unroll
        for (int s = 0; s < 4; s++) *(float4*)&Bs[ak][aj + s * 4] = pb[s];
        __syncthreads();
        #pragma unroll 4
        for (int kk = 0; kk < 32; kk++) {
            float4 a0 = *(const float4*)&As[kk][ty * 8];
            float4 a1 = *(const float4*)&As[kk][ty * 8 + 4];
            float4 b0 = *(const float4*)&Bs[kk][tx * 8];
            float4 b1 = *(const float4*)&Bs[kk][tx * 8 + 4];
            float a[8] = {a0.x, a0.y, a0.z, a0.w, a1.x, a1.y, a1.z, a1.w};
            float w[8] = {b0.x, b0.y, b0.z, b0.w, b1.x, b1.y, b1.z, b1.w};
            #pragma unroll
            for (int mi = 0; mi < 8; mi++)
                #pragma unroll
                for (int ni = 0; ni < 8; ni++)
                    acc[mi][ni] += a[mi] * w[ni];
        }
        __syncthreads();
    }
    #pragma unroll
    for (int mi = 0; mi < 8; mi++) {
        int gm = m0 + ty * 8 + mi;
        float mq = (dmask[(long)b * ND + gm] != 0) ? 1.f : 0.f;
        float* po = out + ((long)b * ND + gm) * DIM + n0 + tx * 8;
        float4 o0; o0.x = mq * acc[mi][0]; o0.y = mq * acc[mi][1]; o0.z = mq * acc[mi][2]; o0.w = mq * acc[mi][3];
        float4 o1; o1.x = mq * acc[mi][4]; o1.y = mq * acc[mi][5]; o1.z = mq * acc[mi][6]; o1.w = mq * acc[mi][7];
        *(float4*)(po) = o0; *(float4*)(po + 4) = o1;
    }
}

// ============ final dc: relu((bits @ (phi+plo) + aggdc) / dc_num) ============
__global__ __launch_bounds__(256) void k_agg_final(
    const unsigned* __restrict__ bits,
    const unsigned short* __restrict__ phi, const unsigned short* __restrict__ plo,
    const float* __restrict__ aggdc, const float* __restrict__ rownum,
    float* __restrict__ out)
{
    int flat = blockIdx.x;
    int tile = (flat & 7) * 128 + (flat >> 3);
    int b = tile >> 6;
    int m0 = ((tile >> 2) & 15) * 128;
    int n0 = (tile & 3) * 128;

    __shared__ unsigned short Aexp[128 * 64];
    __shared__ unsigned short Bhi[128 * 64];
    __shared__ unsigned short Blo[128 * 64];

    int tid = threadIdx.x;
    int lane = tid & 63, wid = tid >> 6;
    int wm = wid >> 1, wn = wid & 1;

    int arow = tid >> 1, awsel = tid & 1;
    const unsigned* abit_base = bits + ((long)b * ND + m0 + arow) * 64 + awsel;

    f32x4 acc[4][4];
    #pragma unroll
    for (int i = 0; i < 4; i++)
        #pragma unroll
        for (int j = 0; j < 4; j++)
            acc[i][j] = (f32x4){0.f, 0.f, 0.f, 0.f};

    for (int k0 = 0; k0 < ND; k0 += 64) {
        #pragma unroll
        for (int u = 0; u < 8; u++) {
            int lin = (u & 3) * 256 + tid;
            int n = lin >> 3, c = lin & 7;
            const unsigned short* src = (u < 4 ? phi : plo)
                + ((long)b * DIM + n0 + n) * ND + k0 + c * 8;
            uint4 v = *(const uint4*)src;
            char* dst = (char*)(u < 4 ? Bhi : Blo) + n * 128 + ((c ^ (n & 7)) * 16);
            *(uint4*)dst = v;
        }
        {
            unsigned w = abit_base[k0 >> 5];
            char* ab = (char*)Aexp + arow * 128;
            #pragma unroll
            for (int c = 0; c < 4; c++) {
                uint4 qv;
                qv.x = (((w >> (c * 8 + 0)) & 1u) ? 0x3F80u : 0u) | (((w >> (c * 8 + 1)) & 1u) ? 0x3F800000u : 0u);
                qv.y = (((w >> (c * 8 + 2)) & 1u) ? 0x3F80u : 0u) | (((w >> (c * 8 + 3)) & 1u) ? 0x3F800000u : 0u);
                qv.z = (((w >> (c * 8 + 4)) & 1u) ? 0x3F80u : 0u) | (((w >> (c * 8 + 5)) & 1u) ? 0x3F800000u : 0u);
                qv.w = (((w >> (c * 8 + 6)) & 1u) ? 0x3F80u : 0u) | (((w >> (c * 8 + 7)) & 1u) ? 0x3F800000u : 0u);
                int chunk = (awsel * 4 + c) ^ (arow & 7);
                *(uint4*)(ab + chunk * 16) = qv;
            }
        }
        __syncthreads();
        #pragma unroll
        for (int ks = 0; ks < 2; ks++) {
            bf16x8 af[4], bh[4], bl[4];
            #pragma unroll
            for (int i = 0; i < 4; i++) {
                int rr = wm * 64 + i * 16 + (lane & 15);
                int cc = (ks * 4 + (lane >> 4)) ^ (rr & 7);
                af[i] = *(bf16x8*)((char*)Aexp + rr * 128 + cc * 16);
                int nn = wn * 64 + i * 16 + (lane & 15);
                int c2 = (ks * 4 + (lane >> 4)) ^ (nn & 7);
                bh[i] = *(bf16x8*)((char*)Bhi + nn * 128 + c2 * 16);
                bl[i] = *(bf16x8*)((char*)Blo + nn * 128 + c2 * 16);
            }
            #pragma unroll
            for (int mi = 0; mi < 4; mi++)
                #pragma unroll
                for (int ni = 0; ni < 4; ni++) {
                    acc[mi][ni] = __builtin_amdgcn_mfma_f32_16x16x32_bf16(af[mi], bh[ni], acc[mi][ni], 0, 0, 0);
                    acc[mi][ni] = __builtin_amdgcn_mfma_f32_16x16x32_bf16(af[mi], bl[ni], acc[mi][ni], 0, 0, 0);
                }
        }
        __syncthreads();
    }
    #pragma unroll
    for (int mi = 0; mi < 4; mi++) {
        int grow = m0 + wm * 64 + mi * 16 + (lane >> 4) * 4;
        float inv[4];
        #pragma unroll
        for (int r = 0; r < 4; r++) inv[r] = 1.f / rownum[(long)b * ND + grow + r];
        #pragma unroll
        for (int ni = 0; ni < 4; ni++) {
            int gcol = n0 + wn * 64 + ni * 16 + (lane & 15);
            #pragma unroll
            for (int r = 0; r < 4; r++) {
                long off = ((long)b * ND + grow + r) * DIM + gcol;
                out[off] = fmaxf((acc[mi][ni][r] + aggdc[off]) * inv[r], 0.f);
            }
        }
    }
}

// ==================================================================================
extern "C" void kernel_launch(void* const* d_in, const int* in_sizes, int n_in,
                              void* d_out, int out_size, void* d_ws, size_t ws_size,
                              hipStream_t stream)
{
    const float* q       = (const float*)d_in[0];
    const float* rh0     = (const float*)d_in[1];
    const float* ch0     = (const float*)d_in[2];
    const float* dc0     = (const float*)d_in[3];
    const int*   rm      = (const int*)d_in[4];
    const int*   cm      = (const int*)d_in[5];
    const int*   dmask   = (const int*)d_in[6];
    const int*   same_row= (const int*)d_in[7];
    const int*   same_col= (const int*)d_in[8];
    const int*   rel_rd  = (const int*)d_in[9];
    const int*   rel_cd  = (const int*)d_in[10];
    const float* wnode   = (const float*)d_in[11];
    const float* w_rdc   = (const float*)d_in[12];
    const float* w_cdc   = (const float*)d_in[13];
    const float* w_dcr   = (const float*)d_in[14];
    const float* w_dcc   = (const float*)d_in[15];
    const float* w_sr    = (const float*)d_in[16];
    const float* w_rq    = (const float*)d_in[18];
    const float* w_cq    = (const float*)d_in[19];

    float* out = (float*)d_out;
    float* rh = out;                           // [16,64,512]
    float* ch = out + (long)NB * NR * DIM;     // [16,64,512]
    float* dc = out + (long)NB * NR * DIM * 2; // [16,2048,512]

    if (ws_size < (size_t)WS_FLOATS * 4) return;

    float* ws      = (float*)d_ws;
    float* rh_num  = ws + OFF_RHNUM;
    float* ch_num  = ws + OFF_CHNUM;
    float* dc_num  = ws + OFF_DCNUM;
    float* rh_w    = ws + OFF_RHW;
    float* ch_w    = ws + OFF_CHW;
    float* qrow    = ws + OFF_QROW;
    float* qcol    = ws + OFF_QCOL;
    float* pre_r   = ws + OFF_PRER;
    float* pre_c   = ws + OFF_PREC;
    float* info_rc = ws + OFF_INFORC;
    unsigned* bits = (unsigned*)(ws + OFF_BITS);
    unsigned short* dhi = (unsigned short*)(ws + OFF_DCS);
    unsigned short* dlo = dhi + (size_t)NB * ND * DIM;
    unsigned short* phi = (unsigned short*)(ws + OFF_PROJ);
    unsigned short* plo = phi + (size_t)NB * DIM * ND;
    float* aggdc   = ws + OFF_DCS;             // alias: dhi/dlo dead before k_aggdc writes
    unsigned short* whi = (unsigned short*)(ws + OFF_PRER);  // alias: pre_r written later
    unsigned short* wlo = whi + (size_t)DIM * DIM;

    hipMemcpyAsync(rh, rh0, sizeof(float) * (size_t)NB * NR * DIM, hipMemcpyDeviceToDevice, stream);
    hipMemcpyAsync(ch, ch0, sizeof(float) * (size_t)NB * NCOL * DIM, hipMemcpyDeviceToDevice, stream);

    k_bits<<<NB * ND, 256, 0, stream>>>(same_row, same_col, dmask, bits, dc_num);
    k_rcnum<<<512, 256, 0, stream>>>(rel_rd, rel_cd, rm, cm, dmask, rh_num, ch_num);
    k_dcnum_final<<<dim3(ND / 256, NB), 256, 0, stream>>>(rel_rd, rel_cd, rm, cm, dmask, dc_num);
    k_q<<<dim3(128, 2, NB), 256, 0, stream>>>(q, w_rq, w_cq, qrow, qcol);

    for (int it = 0; it < 2; it++) {
        k_gate_rc<<<512, 256, 0, stream>>>(rh, ch, rm, cm, wnode, rh_w, ch_w);
        k_split<<<8192, 256, 0, stream>>>(it == 0 ? dc0 : dc, wnode, dmask, dhi, dlo);
        k_wsplit<<<128, 256, 0, stream>>>(w_sr, whi, wlo);
        gemm_small<1><<<dim3(8, 1, NB), 256, 0, stream>>>(rh, (long)NR * DIM, w_dcr,
            info_rc, 128L * DIM, rh_w, 1.0f, nullptr, nullptr, nullptr, NR);
        gemm_small<1><<<dim3(8, 1, NB), 256, 0, stream>>>(ch, (long)NCOL * DIM, w_dcc,
            info_rc + 64L * DIM, 128L * DIM, ch_w, 2.0f, nullptr, nullptr, nullptr, NCOL);
        // proj planes (reads dhi/dlo + whi/wlo, writes phi/plo)
        k_proj_mfma<<<1024, 256, 0, stream>>>(whi, wlo, dhi, dlo, phi, plo);
        // header aggregations (read dhi/dlo; pre_r overwrite kills whi/wlo - ok, proj done)
        k_pre_rc<<<dim3(8, 2, NB), 256, 0, stream>>>(rel_rd, rel_cd, dhi, dlo, rm, cm, pre_r, pre_c);
        // aggdc overwrites dhi/dlo (dead now)
        k_aggdc<<<dim3(4, 16, NB), 256, 0, stream>>>(rel_rd, rel_cd, info_rc, dmask, aggdc);
        gemm_small<2><<<dim3(8, 1, NB), 256, 0, stream>>>(pre_r, (long)NR * DIM, w_rdc,
            rh, (long)NR * DIM, nullptr, 1.0f, rm, qrow, rh_num, NR);
        gemm_small<2><<<dim3(8, 1, NB), 256, 0, stream>>>(pre_c, (long)NCOL * DIM, w_cdc,
            ch, (long)NCOL * DIM, nullptr, 1.0f, cm, qcol, ch_num, NCOL);
        // final dc update
        k_agg_final<<<1024, 256, 0, stream>>>(bits, phi, plo, aggdc, dc_num, dc);
    }
}

// Round 4
// 1147.497 us; speedup vs baseline: 2.1402x; 1.0079x over previous
//
#include <hip/hip_runtime.h>
#include <math.h>

#define NB 16
#define NR 64
#define NCOL 64
#define ND 2048
#define DIM 512

typedef __attribute__((ext_vector_type(4))) float f32x4;
typedef __attribute__((ext_vector_type(8))) short bf16x8;
typedef __attribute__((ext_vector_type(8))) unsigned short us8;

// ---------------- workspace layout (float offsets) ----------------
#define OFF_RHNUM  0L
#define OFF_CHNUM  1024L
#define OFF_DCNUM  2048L
#define OFF_RHW    34816L
#define OFF_CHW    35840L
#define OFF_QROW   36864L
#define OFF_QCOL   45056L
#define OFF_PRER   53248L
#define OFF_PREC   577536L
#define OFF_INFORC 1101824L
#define OFF_BITS   2150400L
#define OFF_DCS    4247552L   // dhi/dlo row-major planes; later aliased as aggdc
#define OFF_PROJ   21024768L  // thi/tlo transposed dcs planes, then phi/plo proj planes
#define WS_FLOATS  37801984L  // 151.2 MB (unchanged)
// whi/wlo live in the out-dc slice (dead mid-iteration)

// RNE fp32 -> bf16 split: v ~= hi + lo, both bf16
__device__ inline void bsplit(float v, unsigned short& h, unsigned short& l) {
    unsigned uv = __float_as_uint(v);
    unsigned hb = (uv + 0x7FFFu + ((uv >> 16) & 1u)) >> 16;
    h = (unsigned short)hb;
    float lo = v - __uint_as_float(hb << 16);
    unsigned lv = __float_as_uint(lo);
    l = (unsigned short)((lv + 0x7FFFu + ((lv >> 16) & 1u)) >> 16);
}

// spread 8 bits to every 4th position of a 32-bit word
__device__ inline unsigned spread4(unsigned x) {
    x = (x | (x << 12)) & 0x000F000Fu;
    x = (x | (x << 6))  & 0x03030303u;
    x = (x | (x << 3))  & 0x11111111u;
    return x;
}

// ============ gate for rh/ch rows ============
__global__ __launch_bounds__(256) void k_gate_rc(
    const float* __restrict__ rh, const float* __restrict__ ch,
    const int* __restrict__ rm, const int* __restrict__ cm,
    const float* __restrict__ wnode,
    float* __restrict__ rh_w, float* __restrict__ ch_w)
{
    int wave = threadIdx.x >> 6, lane = threadIdx.x & 63;
    int idx = blockIdx.x * 4 + wave;   // < 2048
    const float* xrow; float* outw; int mval;
    if (idx < NB * NR) {
        int b = idx >> 6, r = idx & 63;
        xrow = rh + ((long)b * NR + r) * DIM; mval = rm[b * NR + r]; outw = rh_w + b * NR + r;
    } else {
        int tt = idx - NB * NR; int b = tt >> 6, c = tt & 63;
        xrow = ch + ((long)b * NCOL + c) * DIM; mval = cm[b * NCOL + c]; outw = ch_w + b * NCOL + c;
    }
    const float4* px = (const float4*)xrow;
    const float4* pw = (const float4*)wnode;
    float4 xa = px[lane * 2], xb = px[lane * 2 + 1];
    float4 wa = pw[lane * 2], wb = pw[lane * 2 + 1];
    float s = xa.x * wa.x + xa.y * wa.y + xa.z * wa.z + xa.w * wa.w
            + xb.x * wb.x + xb.y * wb.y + xb.z * wb.z + xb.w * wb.w;
    #pragma unroll
    for (int o = 32; o > 0; o >>= 1) s += __shfl_xor(s, o, 64);
    if (lane == 0) {
        float g = 1.f / (1.f + expf(-s));
        *outw = mval ? g : 0.f;
    }
}

// ============ gate+split dc -> dhi/dlo [b][2048][512] AND thi/tlo [b][512][2048] ============
__global__ __launch_bounds__(256) void k_split(
    const float* __restrict__ src, const float* __restrict__ wnode, const int* __restrict__ dmask,
    unsigned short* __restrict__ dhi, unsigned short* __restrict__ dlo,
    unsigned short* __restrict__ thi, unsigned short* __restrict__ tlo)
{
    int b = blockIdx.y, j0 = blockIdx.x * 16;
    __shared__ float X[16 * 512];
    __shared__ float scs[16];
    int t = threadIdx.x;
    int r = t >> 4, u = t & 15;
    const float* row = src + ((long)b * ND + j0 + r) * DIM;
    float part = 0.f;
    #pragma unroll
    for (int i = 0; i < 8; i++) {
        int col = i * 64 + u * 4;
        float4 v = *(const float4*)(row + col);
        float4 w = *(const float4*)(wnode + col);
        part += v.x * w.x + v.y * w.y + v.z * w.z + v.w * w.w;
        *(float4*)&X[r * 512 + (col ^ ((r & 7) * 4))] = v;
    }
    part += __shfl_xor(part, 1, 64);
    part += __shfl_xor(part, 2, 64);
    part += __shfl_xor(part, 4, 64);
    part += __shfl_xor(part, 8, 64);
    if (u == 0) {
        float g = 1.f / (1.f + expf(-part));
        scs[r] = (dmask[(long)b * ND + j0 + r] != 0) ? g : 0.f;
    }
    __syncthreads();
    // row-major planes
    {
        float s = scs[r];
        long ob = ((long)b * ND + j0 + r) * DIM + u * 32;
        #pragma unroll
        for (int g = 0; g < 4; g++) {
            us8 ph, pl;
            #pragma unroll
            for (int e = 0; e < 8; e++) {
                int cc = u * 32 + g * 8 + e;
                float v = X[r * 512 + (cc ^ ((r & 7) * 4))] * s;
                unsigned short hh, ll; bsplit(v, hh, ll);
                ph[e] = hh; pl[e] = ll;
            }
            *(us8*)(dhi + ob + g * 8) = ph;
            *(us8*)(dlo + ob + g * 8) = pl;
        }
    }
    // transposed planes
    #pragma unroll
    for (int h = 0; h < 2; h++) {
        int n = t + h * 256;
        us8 ph0, ph1, pl0, pl1;
        #pragma unroll
        for (int rr = 0; rr < 16; rr++) {
            float v = X[rr * 512 + (n ^ ((rr & 7) * 4))] * scs[rr];
            unsigned short hh, ll; bsplit(v, hh, ll);
            if (rr < 8) { ph0[rr] = hh; pl0[rr] = ll; }
            else        { ph1[rr - 8] = hh; pl1[rr - 8] = ll; }
        }
        long ob = ((long)b * DIM + n) * ND + j0;
        *(us8*)(thi + ob) = ph0; *(us8*)(thi + ob + 8) = ph1;
        *(us8*)(tlo + ob) = pl0; *(us8*)(tlo + ob + 8) = pl1;
    }
}

// ============ split w_sr -> whi/wlo bf16 [512][512] ============
__global__ __launch_bounds__(256) void k_wsplit(
    const float* __restrict__ w, unsigned short* __restrict__ whi, unsigned short* __restrict__ wlo)
{
    long i = ((long)blockIdx.x * 256 + threadIdx.x) * 8;
    float4 a = *(const float4*)(w + i), b4 = *(const float4*)(w + i + 4);
    float v[8] = {a.x, a.y, a.z, a.w, b4.x, b4.y, b4.z, b4.w};
    us8 ph, pl;
    #pragma unroll
    for (int t = 0; t < 8; t++) {
        unsigned short hh, ll; bsplit(v[t], hh, ll);
        ph[t] = hh; pl[t] = ll;
    }
    *(us8*)(whi + i) = ph;
    *(us8*)(wlo + i) = pl;
}

// ============ q projections (once) ============
__global__ __launch_bounds__(256) void k_q(
    const float* __restrict__ q, const float* __restrict__ wrq, const float* __restrict__ wcq,
    float* __restrict__ qrow, float* __restrict__ qcol)
{
    int b = blockIdx.z;
    const float* W = blockIdx.y ? wcq : wrq;
    float* out = blockIdx.y ? qcol : qrow;
    int wave = threadIdx.x >> 6, lane = threadIdx.x & 63;
    int n = blockIdx.x * 4 + wave;
    const float4* qp = (const float4*)(q + (long)b * DIM);
    const float4* wp = (const float4*)(W + (long)n * DIM);
    float4 a0 = qp[lane * 2], a1 = qp[lane * 2 + 1];
    float4 w0 = wp[lane * 2], w1 = wp[lane * 2 + 1];
    float s = a0.x * w0.x + a0.y * w0.y + a0.z * w0.z + a0.w * w0.w
            + a1.x * w1.x + a1.y * w1.y + a1.z * w1.z + a1.w * w1.w;
    #pragma unroll
    for (int o = 32; o > 0; o >>= 1) s += __shfl_xor(s, o, 64);
    if (lane == 0) out[(long)b * DIM + n] = s;
}

// ============ pack same_row bits (vectorized) + partial dc_num ============
__global__ __launch_bounds__(256) void k_bits(
    const int* __restrict__ sr, const int* __restrict__ sc, const int* __restrict__ dmask,
    unsigned* __restrict__ bits, float* __restrict__ dcnum)
{
    long bi = blockIdx.x;                    // = b*ND + i
    int b = (int)(bi >> 11);
    int dmi = dmask[bi];
    int wave = threadIdx.x >> 6, lane = threadIdx.x & 63;
    const int4* sr4 = (const int4*)(sr + bi * ND);
    const int4* sc4 = (const int4*)(sc + bi * ND);
    const int4* dm4 = (const int4*)(dmask + (long)b * ND);
    unsigned* brow = bits + bi * 64;
    int cnt = 0;
    #pragma unroll
    for (int h = 0; h < 2; h++) {
        int vidx = wave * 128 + h * 64 + lane;    // int4 index; j = 4*vidx+k
        int4 vs = sr4[vidx];
        int4 vc = sc4[vidx];
        int4 vd = dm4[vidx];
        bool d0 = dmi && vd.x, d1 = dmi && vd.y, d2 = dmi && vd.z, d3 = dmi && vd.w;
        unsigned long long m0 = __ballot(d0 && vs.x);
        unsigned long long m1 = __ballot(d1 && vs.y);
        unsigned long long m2 = __ballot(d2 && vs.z);
        unsigned long long m3 = __ballot(d3 && vs.w);
        unsigned long long n0 = __ballot(d0 && vc.x);
        unsigned long long n1 = __ballot(d1 && vc.y);
        unsigned long long n2 = __ballot(d2 && vc.z);
        unsigned long long n3 = __ballot(d3 && vc.w);
        cnt += __popcll(m0) + __popcll(m1) + __popcll(m2) + __popcll(m3)
             + __popcll(n0) + __popcll(n1) + __popcll(n2) + __popcll(n3);
        if (lane < 8) {
            // word W covers j = 32W..32W+31; bit 4i+k comes from ballot mk bit (8*lane+i)
            unsigned w = spread4((unsigned)(m0 >> (8 * lane)) & 0xFFu)
                       | (spread4((unsigned)(m1 >> (8 * lane)) & 0xFFu) << 1)
                       | (spread4((unsigned)(m2 >> (8 * lane)) & 0xFFu) << 2)
                       | (spread4((unsigned)(m3 >> (8 * lane)) & 0xFFu) << 3);
            brow[wave * 16 + h * 8 + lane] = w;
        }
    }
    __shared__ int red[4];
    if (lane == 0) red[wave] = cnt;
    __syncthreads();
    if (threadIdx.x == 0) dcnum[bi] = (float)(red[0] + red[1] + red[2] + red[3]);
}

// ============ rh_num / ch_num ============
__global__ __launch_bounds__(256) void k_rcnum(
    const int* __restrict__ rel_rd, const int* __restrict__ rel_cd,
    const int* __restrict__ rm, const int* __restrict__ cm, const int* __restrict__ dmask,
    float* __restrict__ rh_num, float* __restrict__ ch_num)
{
    int wave = threadIdx.x >> 6, lane = threadIdx.x & 63;
    long idx = (long)blockIdx.x * 4 + wave;  // < 2048
    const int* row; int mval; float* out; const int* dmb;
    if (idx < NB * NR) {
        int b = (int)(idx >> 6), r = (int)(idx & 63);
        row = rel_rd + ((long)b * NR + r) * ND; mval = rm[b * NR + r];
        out = rh_num + b * NR + r; dmb = dmask + (long)b * ND;
    } else {
        long tt = idx - NB * NR; int b = (int)(tt >> 6), c = (int)(tt & 63);
        row = rel_cd + ((long)b * NCOL + c) * ND; mval = cm[b * NCOL + c];
        out = ch_num + b * NCOL + c; dmb = dmask + (long)b * ND;
    }
    int cnt = 0;
    for (int rr = 0; rr < 32; rr++) {
        int j = rr * 64 + lane;
        cnt += (row[j] != 0 && dmb[j] != 0) ? 1 : 0;
    }
    #pragma unroll
    for (int o = 32; o > 0; o >>= 1) cnt += __shfl_xor(cnt, o, 64);
    if (lane == 0) {
        float s = mval ? (float)cnt : 0.f;
        *out = (s >= 1.f) ? (s + 1.f) : 1.f;
    }
}

// ============ finalize dc_num ============
__global__ __launch_bounds__(256) void k_dcnum_final(
    const int* __restrict__ rel_rd, const int* __restrict__ rel_cd,
    const int* __restrict__ rm, const int* __restrict__ cm, const int* __restrict__ dmask,
    float* __restrict__ dcnum)
{
    int b = blockIdx.y;
    int j = blockIdx.x * 256 + threadIdx.x;
    const int* rd = rel_rd + (long)b * NR * ND;
    const int* cd = rel_cd + (long)b * NCOL * ND;
    const int* rmb = rm + b * NR;
    const int* cmb = cm + b * NCOL;
    int cnt = 0;
    for (int r = 0; r < NR; r++)  cnt += (rd[(long)r * ND + j] != 0 && rmb[r] != 0) ? 1 : 0;
    for (int c = 0; c < NCOL; c++) cnt += (cd[(long)c * ND + j] != 0 && cmb[c] != 0) ? 1 : 0;
    float add = (dmask[(long)b * ND + j] != 0) ? (float)cnt : 0.f;
    float tv = dcnum[(long)b * ND + j] + add;
    dcnum[(long)b * ND + j] = (tv >= 1.f) ? tv : 1.f;
}

// ============ small dense GEMM: M=64, N=K=512 ============
template<int EPI>
__global__ __launch_bounds__(256) void gemm_small(
    const float* __restrict__ A, long sA,
    const float* __restrict__ W,
    float* __restrict__ C, long sC,
    const float* __restrict__ rowscale, float alpha,
    const int* __restrict__ mrow, const float* __restrict__ addvec,
    const float* __restrict__ rownum, int rsb)
{
    int b = blockIdx.z;
    int n0 = blockIdx.x * 64;
    __shared__ float As[32][68], Ws[32][68];
    float acc[4][4] = {};
    int tx = threadIdx.x & 15, ty = threadIdx.x >> 4;
    int lm = threadIdx.x >> 2, lk = (threadIdx.x & 3) * 8;
    const float* Ab = A + (long)b * sA;
    for (int k0 = 0; k0 < DIM; k0 += 32) {
        const float4* pa = (const float4*)(Ab + (long)lm * DIM + k0 + lk);
        float4 va0 = pa[0], va1 = pa[1];
        const float4* pw = (const float4*)(W + (long)(n0 + lm) * DIM + k0 + lk);
        float4 vw0 = pw[0], vw1 = pw[1];
        As[lk + 0][lm] = va0.x; As[lk + 1][lm] = va0.y; As[lk + 2][lm] = va0.z; As[lk + 3][lm] = va0.w;
        As[lk + 4][lm] = va1.x; As[lk + 5][lm] = va1.y; As[lk + 6][lm] = va1.z; As[lk + 7][lm] = va1.w;
        Ws[lk + 0][lm] = vw0.x; Ws[lk + 1][lm] = vw0.y; Ws[lk + 2][lm] = vw0.z; Ws[lk + 3][lm] = vw0.w;
        Ws[lk + 4][lm] = vw1.x; Ws[lk + 5][lm] = vw1.y; Ws[lk + 6][lm] = vw1.z; Ws[lk + 7][lm] = vw1.w;
        __syncthreads();
        #pragma unroll
        for (int kk = 0; kk < 32; kk++) {
            float4 av = *(const float4*)&As[kk][ty * 4];
            float4 wv = *(const float4*)&Ws[kk][tx * 4];
            float a[4] = {av.x, av.y, av.z, av.w};
            float w[4] = {wv.x, wv.y, wv.z, wv.w};
            #pragma unroll
            for (int mi = 0; mi < 4; mi++)
                #pragma unroll
                for (int ni = 0; ni < 4; ni++)
                    acc[mi][ni] += a[mi] * w[ni];
        }
        __syncthreads();
    }
    #pragma unroll
    for (int mi = 0; mi < 4; mi++) {
        int gm = ty * 4 + mi;
        float vals[4];
        if (EPI == 1) {
            float scv = alpha * rowscale[(long)b * rsb + gm];
            #pragma unroll
            for (int ni = 0; ni < 4; ni++) vals[ni] = scv * acc[mi][ni];
        } else {
            float mq = (mrow[(long)b * rsb + gm] != 0) ? 1.f : 0.f;
            float inv = 1.f / rownum[(long)b * rsb + gm];
            #pragma unroll
            for (int ni = 0; ni < 4; ni++) {
                float tv = (acc[mi][ni] + mq * addvec[(long)b * DIM + n0 + tx * 4 + ni]) * inv;
                vals[ni] = fmaxf(tv, 0.f);
            }
        }
        float4 o; o.x = vals[0]; o.y = vals[1]; o.z = vals[2]; o.w = vals[3];
        *(float4*)(C + (long)b * sC + (long)gm * DIM + n0 + tx * 4) = o;
    }
}

// ============ pre_r/pre_c via MFMA: [rel_rd ; rel_cd] (128x2048) @ dcsum (2048x512) ============
// A = rel int32 expanded to bf16 {0,1}; B from transposed planes thi/tlo (k=j contiguous)
__global__ __launch_bounds__(256) void k_pre_rc_mfma(
    const int* __restrict__ rel_rd, const int* __restrict__ rel_cd,
    const unsigned short* __restrict__ thi, const unsigned short* __restrict__ tlo,
    const int* __restrict__ rm, const int* __restrict__ cm,
    float* __restrict__ pre_r, float* __restrict__ pre_c)
{
    int b = blockIdx.y, n0 = blockIdx.x * 64;
    __shared__ unsigned short Aexp[128 * 64];  // 16 KB, row stride 128B
    __shared__ unsigned short Bhi[64 * 64], Blo[64 * 64];  // 8 KB each
    int tid = threadIdx.x, lane = tid & 63, wid = tid >> 6;
    int wm = wid >> 1, wn = wid & 1;
    int arow = tid >> 1, aseg = tid & 1;
    const int* relrow = (arow < 64)
        ? rel_rd + ((long)b * 64 + arow) * ND
        : rel_cd + ((long)b * 64 + arow - 64) * ND;
    int bn = tid >> 2, bq = tid & 3;
    const unsigned short* bsrc_h = thi + ((long)b * DIM + n0 + bn) * ND;
    const unsigned short* bsrc_l = tlo + ((long)b * DIM + n0 + bn) * ND;

    f32x4 acc[4][2];
    #pragma unroll
    for (int i = 0; i < 4; i++)
        #pragma unroll
        for (int j = 0; j < 2; j++)
            acc[i][j] = (f32x4){0.f, 0.f, 0.f, 0.f};

    for (int k0 = 0; k0 < ND; k0 += 64) {
        // A: 128 rows x 64 j from rel int32
        {
            const int4* pa = (const int4*)(relrow + k0 + aseg * 32);
            #pragma unroll
            for (int p = 0; p < 4; p++) {
                int4 v0 = pa[2 * p], v1 = pa[2 * p + 1];
                uint4 qv;
                qv.x = (v0.x ? 0x3F80u : 0u) | (v0.y ? 0x3F800000u : 0u);
                qv.y = (v0.z ? 0x3F80u : 0u) | (v0.w ? 0x3F800000u : 0u);
                qv.z = (v1.x ? 0x3F80u : 0u) | (v1.y ? 0x3F800000u : 0u);
                qv.w = (v1.z ? 0x3F80u : 0u) | (v1.w ? 0x3F800000u : 0u);
                int c = (aseg * 4 + p) ^ (arow & 7);
                *(uint4*)((char*)Aexp + arow * 128 + c * 16) = qv;
            }
        }
        // B: 64 n-rows x 64 j from thi/tlo
        {
            const uint4* ph = (const uint4*)(bsrc_h + k0 + bq * 16);
            const uint4* pl = (const uint4*)(bsrc_l + k0 + bq * 16);
            #pragma unroll
            for (int s = 0; s < 2; s++) {
                int c = (bq * 2 + s) ^ (bn & 7);
                *(uint4*)((char*)Bhi + bn * 128 + c * 16) = ph[s];
                *(uint4*)((char*)Blo + bn * 128 + c * 16) = pl[s];
            }
        }
        __syncthreads();
        #pragma unroll
        for (int ks = 0; ks < 2; ks++) {
            bf16x8 af[4], bh[2], bl[2];
            #pragma unroll
            for (int i = 0; i < 4; i++) {
                int rr = wm * 64 + i * 16 + (lane & 15);
                int cc = (ks * 4 + (lane >> 4)) ^ (rr & 7);
                af[i] = *(bf16x8*)((char*)Aexp + rr * 128 + cc * 16);
            }
            #pragma unroll
            for (int i = 0; i < 2; i++) {
                int nn = wn * 32 + i * 16 + (lane & 15);
                int c2 = (ks * 4 + (lane >> 4)) ^ (nn & 7);
                bh[i] = *(bf16x8*)((char*)Bhi + nn * 128 + c2 * 16);
                bl[i] = *(bf16x8*)((char*)Blo + nn * 128 + c2 * 16);
            }
            #pragma unroll
            for (int mi = 0; mi < 4; mi++)
                #pragma unroll
                for (int ni = 0; ni < 2; ni++) {
                    acc[mi][ni] = __builtin_amdgcn_mfma_f32_16x16x32_bf16(af[mi], bh[ni], acc[mi][ni], 0, 0, 0);
                    acc[mi][ni] = __builtin_amdgcn_mfma_f32_16x16x32_bf16(af[mi], bl[ni], acc[mi][ni], 0, 0, 0);
                }
        }
        __syncthreads();
    }
    const int* msk = wm ? cm : rm;
    float* outp = wm ? pre_c : pre_r;
    #pragma unroll
    for (int mi = 0; mi < 4; mi++) {
        int grow = mi * 16 + (lane >> 4) * 4;    // local 0..63 (wm selects output)
        #pragma unroll
        for (int ni = 0; ni < 2; ni++) {
            int gcol = n0 + wn * 32 + ni * 16 + (lane & 15);
            #pragma unroll
            for (int r = 0; r < 4; r++) {
                int rrow = grow + r;
                float scv = (msk[b * 64 + rrow] != 0) ? 1.f : 0.f;
                outp[((long)b * 64 + rrow) * DIM + gcol] = scv * acc[mi][ni][r];
            }
        }
    }
}

// ============ projT = Wsr-split @ dcs-split^T via MFMA -> bf16 hi/lo planes [b][512][2048] ============
__global__ __launch_bounds__(256) void k_proj_mfma(
    const unsigned short* __restrict__ whi, const unsigned short* __restrict__ wlo,
    const unsigned short* __restrict__ dhi, const unsigned short* __restrict__ dlo,
    unsigned short* __restrict__ phi, unsigned short* __restrict__ plo)
{
    int flat = blockIdx.x;                   // 1024 blocks
    int tile = (flat & 7) * 128 + (flat >> 3);
    int b = tile >> 6;
    int rem = tile & 63;
    int m0 = (rem >> 4) * 128;               // W-row tile (4)
    int n0 = (rem & 15) * 128;               // cell tile (16)

    __shared__ unsigned short Ahi[128 * 64], Alo[128 * 64];
    __shared__ unsigned short Bhi[128 * 64], Blo[128 * 64];

    int tid = threadIdx.x;
    int lane = tid & 63, wid = tid >> 6;
    int wm = wid >> 1, wn = wid & 1;

    int srow = tid >> 1, sseg = tid & 1;     // staging: (row, 32-k half)

    f32x4 acc[4][4];
    #pragma unroll
    for (int i = 0; i < 4; i++)
        #pragma unroll
        for (int j = 0; j < 4; j++)
            acc[i][j] = (f32x4){0.f, 0.f, 0.f, 0.f};

    for (int k0 = 0; k0 < DIM; k0 += 64) {
        {
            const uint4* ph = (const uint4*)(whi + (long)(m0 + srow) * DIM + k0 + sseg * 32);
            const uint4* pl = (const uint4*)(wlo + (long)(m0 + srow) * DIM + k0 + sseg * 32);
            #pragma unroll
            for (int s = 0; s < 4; s++) {
                int c = (sseg * 4 + s) ^ (srow & 7);
                *(uint4*)((char*)Ahi + srow * 128 + c * 16) = ph[s];
                *(uint4*)((char*)Alo + srow * 128 + c * 16) = pl[s];
            }
        }
        {
            const uint4* ph = (const uint4*)(dhi + ((long)b * ND + n0 + srow) * DIM + k0 + sseg * 32);
            const uint4* pl = (const uint4*)(dlo + ((long)b * ND + n0 + srow) * DIM + k0 + sseg * 32);
            #pragma unroll
            for (int s = 0; s < 4; s++) {
                int c = (sseg * 4 + s) ^ (srow & 7);
                *(uint4*)((char*)Bhi + srow * 128 + c * 16) = ph[s];
                *(uint4*)((char*)Blo + srow * 128 + c * 16) = pl[s];
            }
        }
        __syncthreads();
        #pragma unroll
        for (int ks = 0; ks < 2; ks++) {
            bf16x8 ah[4], al[4], bh[4], bl[4];
            #pragma unroll
            for (int i = 0; i < 4; i++) {
                int rr = wm * 64 + i * 16 + (lane & 15);
                int cc = (ks * 4 + (lane >> 4)) ^ (rr & 7);
                ah[i] = *(bf16x8*)((char*)Ahi + rr * 128 + cc * 16);
                al[i] = *(bf16x8*)((char*)Alo + rr * 128 + cc * 16);
                int nn = wn * 64 + i * 16 + (lane & 15);
                int c2 = (ks * 4 + (lane >> 4)) ^ (nn & 7);
                bh[i] = *(bf16x8*)((char*)Bhi + nn * 128 + c2 * 16);
                bl[i] = *(bf16x8*)((char*)Blo + nn * 128 + c2 * 16);
            }
            #pragma unroll
            for (int mi = 0; mi < 4; mi++)
                #pragma unroll
                for (int ni = 0; ni < 4; ni++) {
                    acc[mi][ni] = __builtin_amdgcn_mfma_f32_16x16x32_bf16(ah[mi], bh[ni], acc[mi][ni], 0, 0, 0);
                    acc[mi][ni] = __builtin_amdgcn_mfma_f32_16x16x32_bf16(ah[mi], bl[ni], acc[mi][ni], 0, 0, 0);
                    acc[mi][ni] = __builtin_amdgcn_mfma_f32_16x16x32_bf16(al[mi], bh[ni], acc[mi][ni], 0, 0, 0);
                }
        }
        __syncthreads();
    }
    #pragma unroll
    for (int mi = 0; mi < 4; mi++) {
        int grow = m0 + wm * 64 + mi * 16 + (lane >> 4) * 4;
        #pragma unroll
        for (int ni = 0; ni < 4; ni++) {
            int gcol = n0 + wn * 64 + ni * 16 + (lane & 15);
            #pragma unroll
            for (int r = 0; r < 4; r++) {
                unsigned short hh, ll; bsplit(acc[mi][ni][r], hh, ll);
                long off = ((long)b * DIM + grow + r) * ND + gcol;
                phi[off] = hh; plo[off] = ll;
            }
        }
    }
}

// ============ aggdc = [rel_rd^T | rel_cd^T] @ info_rc, dm-masked ============
__global__ __launch_bounds__(256) void k_aggdc(
    const int* __restrict__ rel_rd, const int* __restrict__ rel_cd,
    const float* __restrict__ info_rc, const int* __restrict__ dmask,
    float* __restrict__ out)
{
    int b = blockIdx.z, m0 = blockIdx.y * 128, n0 = blockIdx.x * 128;
    __shared__ float As[32][132], Bs[32][132];
    float acc[8][8] = {};
    int tx = threadIdx.x & 15, ty = threadIdx.x >> 4;
    int ak = threadIdx.x >> 3, aj = (threadIdx.x & 7) * 16;
    for (int kt = 0; kt < 4; kt++) {
        const int* rel = (kt < 2) ? rel_rd : rel_cd;
        int krow = (kt & 1) * 32 + ak;
        const int4* pa = (const int4*)(rel + ((long)b * 64 + krow) * ND + m0 + aj);
        #pragma unroll
        for (int s = 0; s < 4; s++) {
            int4 v = pa[s];
            float4 f; f.x = v.x ? 1.f : 0.f; f.y = v.y ? 1.f : 0.f; f.z = v.z ? 1.f : 0.f; f.w = v.w ? 1.f : 0.f;
            *(float4*)&As[ak][aj + s * 4] = f;
        }
        const float4* pb = (const float4*)(info_rc + ((long)b * 128 + kt * 32 + ak) * DIM + n0 + aj);
        #pragma unroll
        for (int s = 0; s < 4; s++) *(float4*)&Bs[ak][aj + s * 4] = pb[s];
        __syncthreads();
        #pragma unroll 4
        for (int kk = 0; kk < 32; kk++) {
            float4 a0 = *(const float4*)&As[kk][ty * 8];
            float4 a1 = *(const float4*)&As[kk][ty * 8 + 4];
            float4 b0 = *(const float4*)&Bs[kk][tx * 8];
            float4 b1 = *(const float4*)&Bs[kk][tx * 8 + 4];
            float a[8] = {a0.x, a0.y, a0.z, a0.w, a1.x, a1.y, a1.z, a1.w};
            float w[8] = {b0.x, b0.y, b0.z, b0.w, b1.x, b1.y, b1.z, b1.w};
            #pragma unroll
            for (int mi = 0; mi < 8; mi++)
                #pragma unroll
                for (int ni = 0; ni < 8; ni++)
                    acc[mi][ni] += a[mi] * w[ni];
        }
        __syncthreads();
    }
    #pragma unroll
    for (int mi = 0; mi < 8; mi++) {
        int gm = m0 + ty * 8 + mi;
        float mq = (dmask[(long)b * ND + gm] != 0) ? 1.f : 0.f;
        float* po = out + ((long)b * ND + gm) * DIM + n0 + tx * 8;
        float4 o0; o0.x = mq * acc[mi][0]; o0.y = mq * acc[mi][1]; o0.z = mq * acc[mi][2]; o0.w = mq * acc[mi][3];
        float4 o1; o1.x = mq * acc[mi][4]; o1.y = mq * acc[mi][5]; o1.z = mq * acc[mi][6]; o1.w = mq * acc[mi][7];
        *(float4*)(po) = o0; *(float4*)(po + 4) = o1;
    }
}

// ============ final dc: relu((bits @ (phi+plo) + aggdc) / dc_num) ============
__global__ __launch_bounds__(256) void k_agg_final(
    const unsigned* __restrict__ bits,
    const unsigned short* __restrict__ phi, const unsigned short* __restrict__ plo,
    const float* __restrict__ aggdc, const float* __restrict__ rownum,
    float* __restrict__ out)
{
    int flat = blockIdx.x;
    int tile = (flat & 7) * 128 + (flat >> 3);
    int b = tile >> 6;
    int m0 = ((tile >> 2) & 15) * 128;
    int n0 = (tile & 3) * 128;

    __shared__ unsigned short Aexp[128 * 64];
    __shared__ unsigned short Bhi[128 * 64];
    __shared__ unsigned short Blo[128 * 64];

    int tid = threadIdx.x;
    int lane = tid & 63, wid = tid >> 6;
    int wm = wid >> 1, wn = wid & 1;

    int arow = tid >> 1, awsel = tid & 1;
    const unsigned* abit_base = bits + ((long)b * ND + m0 + arow) * 64 + awsel;

    f32x4 acc[4][4];
    #pragma unroll
    for (int i = 0; i < 4; i++)
        #pragma unroll
        for (int j = 0; j < 4; j++)
            acc[i][j] = (f32x4){0.f, 0.f, 0.f, 0.f};

    for (int k0 = 0; k0 < ND; k0 += 64) {
        #pragma unroll
        for (int u = 0; u < 8; u++) {
            int lin = (u & 3) * 256 + tid;
            int n = lin >> 3, c = lin & 7;
            const unsigned short* src = (u < 4 ? phi : plo)
                + ((long)b * DIM + n0 + n) * ND + k0 + c * 8;
            uint4 v = *(const uint4*)src;
            char* dst = (char*)(u < 4 ? Bhi : Blo) + n * 128 + ((c ^ (n & 7)) * 16);
            *(uint4*)dst = v;
        }
        {
            unsigned w = abit_base[k0 >> 5];
            char* ab = (char*)Aexp + arow * 128;
            #pragma unroll
            for (int c = 0; c < 4; c++) {
                uint4 qv;
                qv.x = (((w >> (c * 8 + 0)) & 1u) ? 0x3F80u : 0u) | (((w >> (c * 8 + 1)) & 1u) ? 0x3F800000u : 0u);
                qv.y = (((w >> (c * 8 + 2)) & 1u) ? 0x3F80u : 0u) | (((w >> (c * 8 + 3)) & 1u) ? 0x3F800000u : 0u);
                qv.z = (((w >> (c * 8 + 4)) & 1u) ? 0x3F80u : 0u) | (((w >> (c * 8 + 5)) & 1u) ? 0x3F800000u : 0u);
                qv.w = (((w >> (c * 8 + 6)) & 1u) ? 0x3F80u : 0u) | (((w >> (c * 8 + 7)) & 1u) ? 0x3F800000u : 0u);
                int chunk = (awsel * 4 + c) ^ (arow & 7);
                *(uint4*)(ab + chunk * 16) = qv;
            }
        }
        __syncthreads();
        #pragma unroll
        for (int ks = 0; ks < 2; ks++) {
            bf16x8 af[4], bh[4], bl[4];
            #pragma unroll
            for (int i = 0; i < 4; i++) {
                int rr = wm * 64 + i * 16 + (lane & 15);
                int cc = (ks * 4 + (lane >> 4)) ^ (rr & 7);
                af[i] = *(bf16x8*)((char*)Aexp + rr * 128 + cc * 16);
                int nn = wn * 64 + i * 16 + (lane & 15);
                int c2 = (ks * 4 + (lane >> 4)) ^ (nn & 7);
                bh[i] = *(bf16x8*)((char*)Bhi + nn * 128 + c2 * 16);
                bl[i] = *(bf16x8*)((char*)Blo + nn * 128 + c2 * 16);
            }
            #pragma unroll
            for (int mi = 0; mi < 4; mi++)
                #pragma unroll
                for (int ni = 0; ni < 4; ni++) {
                    acc[mi][ni] = __builtin_amdgcn_mfma_f32_16x16x32_bf16(af[mi], bh[ni], acc[mi][ni], 0, 0, 0);
                    acc[mi][ni] = __builtin_amdgcn_mfma_f32_16x16x32_bf16(af[mi], bl[ni], acc[mi][ni], 0, 0, 0);
                }
        }
        __syncthreads();
    }
    #pragma unroll
    for (int mi = 0; mi < 4; mi++) {
        int grow = m0 + wm * 64 + mi * 16 + (lane >> 4) * 4;
        float inv[4];
        #pragma unroll
        for (int r = 0; r < 4; r++) inv[r] = 1.f / rownum[(long)b * ND + grow + r];
        #pragma unroll
        for (int ni = 0; ni < 4; ni++) {
            int gcol = n0 + wn * 64 + ni * 16 + (lane & 15);
            #pragma unroll
            for (int r = 0; r < 4; r++) {
                long off = ((long)b * ND + grow + r) * DIM + gcol;
                out[off] = fmaxf((acc[mi][ni][r] + aggdc[off]) * inv[r], 0.f);
            }
        }
    }
}

// ==================================================================================
extern "C" void kernel_launch(void* const* d_in, const int* in_sizes, int n_in,
                              void* d_out, int out_size, void* d_ws, size_t ws_size,
                              hipStream_t stream)
{
    const float* q       = (const float*)d_in[0];
    const float* rh0     = (const float*)d_in[1];
    const float* ch0     = (const float*)d_in[2];
    const float* dc0     = (const float*)d_in[3];
    const int*   rm      = (const int*)d_in[4];
    const int*   cm      = (const int*)d_in[5];
    const int*   dmask   = (const int*)d_in[6];
    const int*   same_row= (const int*)d_in[7];
    const int*   same_col= (const int*)d_in[8];
    const int*   rel_rd  = (const int*)d_in[9];
    const int*   rel_cd  = (const int*)d_in[10];
    const float* wnode   = (const float*)d_in[11];
    const float* w_rdc   = (const float*)d_in[12];
    const float* w_cdc   = (const float*)d_in[13];
    const float* w_dcr   = (const float*)d_in[14];
    const float* w_dcc   = (const float*)d_in[15];
    const float* w_sr    = (const float*)d_in[16];
    const float* w_rq    = (const float*)d_in[18];
    const float* w_cq    = (const float*)d_in[19];

    float* out = (float*)d_out;
    float* rh = out;                           // [16,64,512]
    float* ch = out + (long)NB * NR * DIM;     // [16,64,512]
    float* dc = out + (long)NB * NR * DIM * 2; // [16,2048,512]

    if (ws_size < (size_t)WS_FLOATS * 4) return;

    float* ws      = (float*)d_ws;
    float* rh_num  = ws + OFF_RHNUM;
    float* ch_num  = ws + OFF_CHNUM;
    float* dc_num  = ws + OFF_DCNUM;
    float* rh_w    = ws + OFF_RHW;
    float* ch_w    = ws + OFF_CHW;
    float* qrow    = ws + OFF_QROW;
    float* qcol    = ws + OFF_QCOL;
    float* pre_r   = ws + OFF_PRER;
    float* pre_c   = ws + OFF_PREC;
    float* info_rc = ws + OFF_INFORC;
    unsigned* bits = (unsigned*)(ws + OFF_BITS);
    unsigned short* dhi = (unsigned short*)(ws + OFF_DCS);
    unsigned short* dlo = dhi + (size_t)NB * ND * DIM;
    unsigned short* thi = (unsigned short*)(ws + OFF_PROJ);  // transposed dcs planes
    unsigned short* tlo = thi + (size_t)NB * DIM * ND;
    unsigned short* phi = (unsigned short*)(ws + OFF_PROJ);  // proj planes overwrite thi/tlo (dead)
    unsigned short* plo = phi + (size_t)NB * DIM * ND;
    float* aggdc   = ws + OFF_DCS;             // alias: dhi/dlo dead before k_aggdc writes
    // whi/wlo live in the out-dc slice (1 MB of 67 MB; dead between k_split and k_agg_final)
    unsigned short* whi = (unsigned short*)dc;
    unsigned short* wlo = whi + (size_t)DIM * DIM;

    hipMemcpyAsync(rh, rh0, sizeof(float) * (size_t)NB * NR * DIM, hipMemcpyDeviceToDevice, stream);
    hipMemcpyAsync(ch, ch0, sizeof(float) * (size_t)NB * NCOL * DIM, hipMemcpyDeviceToDevice, stream);

    k_bits<<<NB * ND, 256, 0, stream>>>(same_row, same_col, dmask, bits, dc_num);
    k_rcnum<<<512, 256, 0, stream>>>(rel_rd, rel_cd, rm, cm, dmask, rh_num, ch_num);
    k_dcnum_final<<<dim3(ND / 256, NB), 256, 0, stream>>>(rel_rd, rel_cd, rm, cm, dmask, dc_num);
    k_q<<<dim3(128, 2, NB), 256, 0, stream>>>(q, w_rq, w_cq, qrow, qcol);

    for (int it = 0; it < 2; it++) {
        k_gate_rc<<<512, 256, 0, stream>>>(rh, ch, rm, cm, wnode, rh_w, ch_w);
        // reads dc (out slice for it=1), then whi/wlo may be written into out-dc
        k_split<<<dim3(128, NB), 256, 0, stream>>>(it == 0 ? dc0 : dc, wnode, dmask, dhi, dlo, thi, tlo);
        k_wsplit<<<128, 256, 0, stream>>>(w_sr, whi, wlo);
        gemm_small<1><<<dim3(8, 1, NB), 256, 0, stream>>>(rh, (long)NR * DIM, w_dcr,
            info_rc, 128L * DIM, rh_w, 1.0f, nullptr, nullptr, nullptr, NR);
        gemm_small<1><<<dim3(8, 1, NB), 256, 0, stream>>>(ch, (long)NCOL * DIM, w_dcc,
            info_rc + 64L * DIM, 128L * DIM, ch_w, 2.0f, nullptr, nullptr, nullptr, NCOL);
        // header pre-aggregations consume thi/tlo ...
        k_pre_rc_mfma<<<dim3(8, NB), 256, 0, stream>>>(rel_rd, rel_cd, thi, tlo, rm, cm, pre_r, pre_c);
        // ... then proj planes overwrite thi/tlo region
        k_proj_mfma<<<1024, 256, 0, stream>>>(whi, wlo, dhi, dlo, phi, plo);
        // aggdc overwrites dhi/dlo (dead now)
        k_aggdc<<<dim3(4, 16, NB), 256, 0, stream>>>(rel_rd, rel_cd, info_rc, dmask, aggdc);
        gemm_small<2><<<dim3(8, 1, NB), 256, 0, stream>>>(pre_r, (long)NR * DIM, w_rdc,
            rh, (long)NR * DIM, nullptr, 1.0f, rm, qrow, rh_num, NR);
        gemm_small<2><<<dim3(8, 1, NB), 256, 0, stream>>>(pre_c, (long)NCOL * DIM, w_cdc,
            ch, (long)NCOL * DIM, nullptr, 1.0f, cm, qcol, ch_num, NCOL);
        // final dc update (overwrites whi/wlo region - they're dead)
        k_agg_final<<<1024, 256, 0, stream>>>(bits, phi, plo, aggdc, dc_num, dc);
    }
}